// Round 1
// baseline (1275.093 us; speedup 1.0000x reference)
//
#include <hip/hip_runtime.h>
#include <hip/hip_bf16.h>

#define NN 100000
#define NE 1600000
#define NG 512
#define HID 128

// ---------------- degree count (in-degree by dst) ----------------
__global__ void k_count(const int* __restrict__ dst, int* __restrict__ cnt) {
  int e = blockIdx.x * 256 + threadIdx.x;
  if (e < NE) atomicAdd(&cnt[dst[e]], 1);
}

// ---------------- single-block prefix scan -> offsets, cursor, dinv ----------------
__global__ __launch_bounds__(1024) void k_scan(const int* __restrict__ cnt,
                                               int* __restrict__ offsets,
                                               int* __restrict__ cursor,
                                               float* __restrict__ dinv) {
  __shared__ int wsum[16];
  __shared__ int carry_s;
  int t = threadIdx.x;
  int lane = t & 63, wid = t >> 6;
  if (t == 0) carry_s = 0;
  __syncthreads();
  for (int base = 0; base < NN; base += 1024) {
    int i = base + t;
    int v = (i < NN) ? cnt[i] : 0;
    // wave-inclusive scan
    int iv = v;
    for (int o = 1; o < 64; o <<= 1) {
      int n = __shfl_up(iv, o, 64);
      if (lane >= o) iv += n;
    }
    if (lane == 63) wsum[wid] = iv;
    __syncthreads();
    if (wid == 0 && lane < 16) {
      int w = wsum[lane];
      for (int o = 1; o < 16; o <<= 1) {
        int n = __shfl_up(w, o, 64);
        if (lane >= o) w += n;
      }
      wsum[lane] = w;
    }
    __syncthreads();
    int incl = iv + (wid ? wsum[wid - 1] : 0);
    int total = wsum[15];
    int carry = carry_s;
    if (i < NN) {
      int o = carry + incl - v;  // exclusive
      offsets[i] = o;
      cursor[i] = o;
      dinv[i] = 1.0f / sqrtf((float)(v + 1));  // deg = 1 (self-loop) + in-count
    }
    __syncthreads();
    if (t == 0) carry_s = carry + total;
    __syncthreads();
  }
  if (t == 0) offsets[NN] = carry_s;
}

// ---------------- bucket edges by dst ----------------
__global__ void k_bucket(const int* __restrict__ src, const int* __restrict__ dst,
                         int* __restrict__ cursor, int* __restrict__ srcs) {
  int e = blockIdx.x * 256 + threadIdx.x;
  if (e < NE) {
    int p = atomicAdd(&cursor[dst[e]], 1);
    srcs[p] = src[e];
  }
}

// ---------------- f32 GEMM: H[N,128] = X[N,128] @ W[128,128] ----------------
// BM=128 rows/block, BK=32, 256 threads, 8x8 register tile.
__global__ __launch_bounds__(256) void k_gemm(const float* __restrict__ X,
                                              const float* __restrict__ W,
                                              float* __restrict__ H) {
  __shared__ float sX[32][128];  // [k][node] (transposed tile)
  __shared__ float sW[32][128];  // [k][col]
  int t = threadIdx.x;
  int row0 = blockIdx.x * 128;
  int tc = (t & 15) * 8;
  int tr = (t >> 4) * 8;
  float acc[8][8];
#pragma unroll
  for (int i = 0; i < 8; ++i)
#pragma unroll
    for (int j = 0; j < 8; ++j) acc[i][j] = 0.f;

  for (int kb = 0; kb < 128; kb += 32) {
// X tile: 128 rows x 8 float4, write transposed into sX
#pragma unroll
    for (int l = 0; l < 4; ++l) {
      int idx = t + l * 256;       // 0..1023
      int r = idx >> 3;            // row 0..127
      int kq = idx & 7;            // float4 index within 32-wide k chunk
      int gr = row0 + r;
      float4 v = make_float4(0.f, 0.f, 0.f, 0.f);
      if (gr < NN) v = ((const float4*)(X + (size_t)gr * 128 + kb))[kq];
      sX[4 * kq + 0][r] = v.x;
      sX[4 * kq + 1][r] = v.y;
      sX[4 * kq + 2][r] = v.z;
      sX[4 * kq + 3][r] = v.w;
    }
// W tile: direct copy, 32 rows x 128 cols = 1024 float4
#pragma unroll
    for (int l = 0; l < 4; ++l) {
      int idx = t + l * 256;
      ((float4*)sW)[idx] = ((const float4*)(W + kb * 128))[idx];
    }
    __syncthreads();
#pragma unroll
    for (int k = 0; k < 32; ++k) {
      float xv[8], wv[8];
      *(float4*)&xv[0] = *(float4*)&sX[k][tr];
      *(float4*)&xv[4] = *(float4*)&sX[k][tr + 4];
      *(float4*)&wv[0] = *(float4*)&sW[k][tc];
      *(float4*)&wv[4] = *(float4*)&sW[k][tc + 4];
#pragma unroll
      for (int i = 0; i < 8; ++i)
#pragma unroll
        for (int j = 0; j < 8; ++j) acc[i][j] += xv[i] * wv[j];
    }
    __syncthreads();
  }
#pragma unroll
  for (int i = 0; i < 8; ++i) {
    int gr = row0 + tr + i;
    if (gr < NN) {
      float4 o0 = make_float4(acc[i][0], acc[i][1], acc[i][2], acc[i][3]);
      float4 o1 = make_float4(acc[i][4], acc[i][5], acc[i][6], acc[i][7]);
      *(float4*)(H + (size_t)gr * 128 + tc) = o0;
      *(float4*)(H + (size_t)gr * 128 + tc + 4) = o1;
    }
  }
}

// ---------------- pull-mode aggregation: out = norm-agg + self-loop + bias (+relu) ----------------
__global__ __launch_bounds__(256) void k_agg(const float* __restrict__ H,
                                             const float* __restrict__ bias,
                                             const float* __restrict__ dinv,
                                             const int* __restrict__ offsets,
                                             const int* __restrict__ srcs,
                                             float* __restrict__ Hout, int do_relu) {
  int node = blockIdx.x * 2 + (threadIdx.x >> 7);
  int c = threadIdx.x & 127;
  if (node >= NN) return;
  float di = dinv[node];
  int s = offsets[node], e = offsets[node + 1];
  float acc = 0.f;
  int i = s;
  for (; i + 1 < e; i += 2) {
    int s0 = srcs[i], s1 = srcs[i + 1];
    float d0 = dinv[s0], d1 = dinv[s1];
    acc += H[(size_t)s0 * 128 + c] * d0;
    acc += H[(size_t)s1 * 128 + c] * d1;
  }
  if (i < e) {
    int s0 = srcs[i];
    acc += H[(size_t)s0 * 128 + c] * dinv[s0];
  }
  acc = acc * di + H[(size_t)node * 128 + c] * (di * di) + bias[c];
  if (do_relu) acc = fmaxf(acc, 0.f);
  Hout[(size_t)node * 128 + c] = acc;
}

// ---------------- global mean pool (batch is sorted) ----------------
__device__ inline int lower_bound(const int* a, int n, int v) {
  int lo = 0, hi = n;
  while (lo < hi) {
    int m = (lo + hi) >> 1;
    if (a[m] < v) lo = m + 1; else hi = m;
  }
  return lo;
}

__global__ __launch_bounds__(128) void k_pool(const float* __restrict__ H,
                                              const int* __restrict__ batch,
                                              float* __restrict__ f) {
  int g = blockIdx.x;
  int c = threadIdx.x;
  int s = lower_bound(batch, NN, g);
  int e = lower_bound(batch, NN, g + 1);
  float acc = 0.f;
  for (int i = s; i < e; ++i) acc += H[(size_t)i * 128 + c];
  f[g * 128 + c] = acc / fmaxf((float)(e - s), 1.0f);
}

// ---------------- MLP head: one block per graph ----------------
__global__ __launch_bounds__(512) void k_mlp(const float* __restrict__ f,
    const float* __restrict__ W1, const float* __restrict__ b1,
    const float* __restrict__ W2, const float* __restrict__ b2,
    const float* __restrict__ W3, const float* __restrict__ b3,
    const float* __restrict__ W4, const float* __restrict__ b4,
    float* __restrict__ z) {
  __shared__ float s0[128];
  __shared__ float s1[512];
  __shared__ float s2[256];
  __shared__ float s3[128];
  int g = blockIdx.x;
  int t = threadIdx.x;
  if (t < 128) s0[t] = f[g * 128 + t];
  __syncthreads();
  {
    float a = b1[t];
#pragma unroll 4
    for (int k = 0; k < 128; ++k) a += s0[k] * W1[k * 512 + t];
    s1[t] = fmaxf(a, 0.f);
  }
  __syncthreads();
  if (t < 256) {
    float a = b2[t];
#pragma unroll 4
    for (int k = 0; k < 512; ++k) a += s1[k] * W2[k * 256 + t];
    s2[t] = fmaxf(a, 0.f);
  }
  __syncthreads();
  if (t < 128) {
    float a = b3[t];
#pragma unroll 4
    for (int k = 0; k < 256; ++k) a += s2[k] * W3[k * 128 + t];
    s3[t] = fmaxf(a, 0.f);
  }
  __syncthreads();
  if (t < 64) {
    float a = b4[t];
#pragma unroll 4
    for (int k = 0; k < 128; ++k) a += s3[k] * W4[k * 64 + t];
    z[g * 64 + t] = a;
  }
}

extern "C" void kernel_launch(void* const* d_in, const int* in_sizes, int n_in,
                              void* d_out, int out_size, void* d_ws, size_t ws_size,
                              hipStream_t stream) {
  const float* x    = (const float*)d_in[0];
  const int* ei     = (const int*)d_in[1];
  const int* batch  = (const int*)d_in[2];
  const float* W1   = (const float*)d_in[3];  const float* b1  = (const float*)d_in[4];
  const float* W2   = (const float*)d_in[5];  const float* b2  = (const float*)d_in[6];
  const float* W3   = (const float*)d_in[7];  const float* b3  = (const float*)d_in[8];
  const float* Wf1  = (const float*)d_in[9];  const float* bf1 = (const float*)d_in[10];
  const float* Wf2  = (const float*)d_in[11]; const float* bf2 = (const float*)d_in[12];
  const float* Wf3  = (const float*)d_in[13]; const float* bf3 = (const float*)d_in[14];
  const float* Wf4  = (const float*)d_in[15]; const float* bf4 = (const float*)d_in[16];
  const int* src = ei;
  const int* dst = ei + NE;

  char* ws = (char*)d_ws;
  size_t off = 0;
  auto alloc = [&](size_t bytes) {
    void* p = ws + off;
    off += (bytes + 255) & ~(size_t)255;
    return p;
  };
  float* hA      = (float*)alloc((size_t)NN * 128 * 4);
  float* hB      = (float*)alloc((size_t)NN * 128 * 4);
  float* dinv    = (float*)alloc((size_t)NN * 4);
  int*   cnt     = (int*)alloc((size_t)NN * 4);
  int*   offsets = (int*)alloc((size_t)(NN + 1) * 4);
  int*   cursor  = (int*)alloc((size_t)NN * 4);
  int*   srcs    = (int*)alloc((size_t)NE * 4);

  float* f_out = (float*)d_out;                 // [512*128]
  float* z_out = (float*)d_out + NG * HID;      // [512*64]

  hipMemsetAsync(cnt, 0, (size_t)NN * 4, stream);
  k_count<<<(NE + 255) / 256, 256, 0, stream>>>(dst, cnt);
  k_scan<<<1, 1024, 0, stream>>>(cnt, offsets, cursor, dinv);
  k_bucket<<<(NE + 255) / 256, 256, 0, stream>>>(src, dst, cursor, srcs);

  int gemm_grid = (NN + 127) / 128;
  int agg_grid = (NN + 1) / 2;

  // layer 1
  k_gemm<<<gemm_grid, 256, 0, stream>>>(x, W1, hA);
  k_agg<<<agg_grid, 256, 0, stream>>>(hA, b1, dinv, offsets, srcs, hB, 1);
  // layer 2
  k_gemm<<<gemm_grid, 256, 0, stream>>>(hB, W2, hA);
  k_agg<<<agg_grid, 256, 0, stream>>>(hA, b2, dinv, offsets, srcs, hB, 1);
  // layer 3
  k_gemm<<<gemm_grid, 256, 0, stream>>>(hB, W3, hA);
  k_agg<<<agg_grid, 256, 0, stream>>>(hA, b3, dinv, offsets, srcs, hB, 0);

  k_pool<<<NG, 128, 0, stream>>>(hB, batch, f_out);
  k_mlp<<<NG, 512, 0, stream>>>(f_out, Wf1, bf1, Wf2, bf2, Wf3, bf3, Wf4, bf4, z_out);
}

// Round 2
// 1012.109 us; speedup vs baseline: 1.2598x; 1.2598x over previous
//
#include <hip/hip_runtime.h>
#include <hip/hip_bf16.h>

#define NN 100000
#define NE 1600000
#define NG 512
#define HID 128

// ---------------- degree count (in-degree by dst) ----------------
__global__ void k_count(const int* __restrict__ dst, int* __restrict__ cnt) {
  int e = blockIdx.x * 256 + threadIdx.x;
  if (e < NE) atomicAdd(&cnt[dst[e]], 1);
}

// ---------------- single-block prefix scan -> offsets, cursor, dinv ----------------
__global__ __launch_bounds__(1024) void k_scan(const int* __restrict__ cnt,
                                               int* __restrict__ offsets,
                                               int* __restrict__ cursor,
                                               float* __restrict__ dinv) {
  __shared__ int wsum[16];
  __shared__ int carry_s;
  int t = threadIdx.x;
  int lane = t & 63, wid = t >> 6;
  if (t == 0) carry_s = 0;
  __syncthreads();
  for (int base = 0; base < NN; base += 1024) {
    int i = base + t;
    int v = (i < NN) ? cnt[i] : 0;
    int iv = v;
    for (int o = 1; o < 64; o <<= 1) {
      int n = __shfl_up(iv, o, 64);
      if (lane >= o) iv += n;
    }
    if (lane == 63) wsum[wid] = iv;
    __syncthreads();
    if (wid == 0 && lane < 16) {
      int w = wsum[lane];
      for (int o = 1; o < 16; o <<= 1) {
        int n = __shfl_up(w, o, 64);
        if (lane >= o) w += n;
      }
      wsum[lane] = w;
    }
    __syncthreads();
    int incl = iv + (wid ? wsum[wid - 1] : 0);
    int total = wsum[15];
    int carry = carry_s;
    if (i < NN) {
      int o = carry + incl - v;  // exclusive
      offsets[i] = o;
      cursor[i] = o;
      dinv[i] = 1.0f / sqrtf((float)(v + 1));  // deg = 1 (self-loop) + in-count
    }
    __syncthreads();
    if (t == 0) carry_s = carry + total;
    __syncthreads();
  }
  if (t == 0) offsets[NN] = carry_s;
}

// ---------------- bucket edges by dst ----------------
__global__ void k_bucket(const int* __restrict__ src, const int* __restrict__ dst,
                         int* __restrict__ cursor, int* __restrict__ srcs) {
  int e = blockIdx.x * 256 + threadIdx.x;
  if (e < NE) {
    int p = atomicAdd(&cursor[dst[e]], 1);
    srcs[p] = src[e];
  }
}

// ---------------- f32 GEMM: H[N,128] = X[N,128] @ W[128,128] ----------------
__global__ __launch_bounds__(256) void k_gemm(const float* __restrict__ X,
                                              const float* __restrict__ W,
                                              float* __restrict__ H) {
  __shared__ float sX[32][128];
  __shared__ float sW[32][128];
  int t = threadIdx.x;
  int row0 = blockIdx.x * 128;
  int tc = (t & 15) * 8;
  int tr = (t >> 4) * 8;
  float acc[8][8];
#pragma unroll
  for (int i = 0; i < 8; ++i)
#pragma unroll
    for (int j = 0; j < 8; ++j) acc[i][j] = 0.f;

  for (int kb = 0; kb < 128; kb += 32) {
#pragma unroll
    for (int l = 0; l < 4; ++l) {
      int idx = t + l * 256;
      int r = idx >> 3;
      int kq = idx & 7;
      int gr = row0 + r;
      float4 v = make_float4(0.f, 0.f, 0.f, 0.f);
      if (gr < NN) v = ((const float4*)(X + (size_t)gr * 128 + kb))[kq];
      sX[4 * kq + 0][r] = v.x;
      sX[4 * kq + 1][r] = v.y;
      sX[4 * kq + 2][r] = v.z;
      sX[4 * kq + 3][r] = v.w;
    }
#pragma unroll
    for (int l = 0; l < 4; ++l) {
      int idx = t + l * 256;
      ((float4*)sW)[idx] = ((const float4*)(W + kb * 128))[idx];
    }
    __syncthreads();
#pragma unroll
    for (int k = 0; k < 32; ++k) {
      float xv[8], wv[8];
      *(float4*)&xv[0] = *(float4*)&sX[k][tr];
      *(float4*)&xv[4] = *(float4*)&sX[k][tr + 4];
      *(float4*)&wv[0] = *(float4*)&sW[k][tc];
      *(float4*)&wv[4] = *(float4*)&sW[k][tc + 4];
#pragma unroll
      for (int i = 0; i < 8; ++i)
#pragma unroll
        for (int j = 0; j < 8; ++j) acc[i][j] += xv[i] * wv[j];
    }
    __syncthreads();
  }
#pragma unroll
  for (int i = 0; i < 8; ++i) {
    int gr = row0 + tr + i;
    if (gr < NN) {
      float4 o0 = make_float4(acc[i][0], acc[i][1], acc[i][2], acc[i][3]);
      float4 o1 = make_float4(acc[i][4], acc[i][5], acc[i][6], acc[i][7]);
      *(float4*)(H + (size_t)gr * 128 + tc) = o0;
      *(float4*)(H + (size_t)gr * 128 + tc + 4) = o1;
    }
  }
}

// ---------------- pull-mode aggregation, float4 lanes, 4-edge unroll ----------------
// 32-lane group per node, 8 nodes per 256-thread block.
__global__ __launch_bounds__(256) void k_agg(const float4* __restrict__ H4,
                                             const float4* __restrict__ bias4,
                                             const float* __restrict__ dinv,
                                             const int* __restrict__ offsets,
                                             const int* __restrict__ srcs,
                                             float4* __restrict__ Hout4, int do_relu) {
  int node = blockIdx.x * 8 + (threadIdx.x >> 5);
  if (node >= NN) return;
  int c = threadIdx.x & 31;  // float4 slot 0..31 (channels 4c..4c+3)
  float di = dinv[node];
  int s = offsets[node], e = offsets[node + 1];
  float4 acc = make_float4(0.f, 0.f, 0.f, 0.f);
  int i = s;
  for (; i + 3 < e; i += 4) {
    int s0 = srcs[i], s1 = srcs[i + 1], s2 = srcs[i + 2], s3 = srcs[i + 3];
    float d0 = dinv[s0], d1 = dinv[s1], d2 = dinv[s2], d3 = dinv[s3];
    float4 v0 = H4[(size_t)s0 * 32 + c];
    float4 v1 = H4[(size_t)s1 * 32 + c];
    float4 v2 = H4[(size_t)s2 * 32 + c];
    float4 v3 = H4[(size_t)s3 * 32 + c];
    acc.x += v0.x * d0 + v1.x * d1 + v2.x * d2 + v3.x * d3;
    acc.y += v0.y * d0 + v1.y * d1 + v2.y * d2 + v3.y * d3;
    acc.z += v0.z * d0 + v1.z * d1 + v2.z * d2 + v3.z * d3;
    acc.w += v0.w * d0 + v1.w * d1 + v2.w * d2 + v3.w * d3;
  }
  for (; i < e; ++i) {
    int s0 = srcs[i];
    float d0 = dinv[s0];
    float4 v0 = H4[(size_t)s0 * 32 + c];
    acc.x += v0.x * d0;
    acc.y += v0.y * d0;
    acc.z += v0.z * d0;
    acc.w += v0.w * d0;
  }
  float4 h = H4[(size_t)node * 32 + c];
  float4 b = bias4[c];
  float dii = di * di;
  acc.x = acc.x * di + h.x * dii + b.x;
  acc.y = acc.y * di + h.y * dii + b.y;
  acc.z = acc.z * di + h.z * dii + b.z;
  acc.w = acc.w * di + h.w * dii + b.w;
  if (do_relu) {
    acc.x = fmaxf(acc.x, 0.f);
    acc.y = fmaxf(acc.y, 0.f);
    acc.z = fmaxf(acc.z, 0.f);
    acc.w = fmaxf(acc.w, 0.f);
  }
  Hout4[(size_t)node * 32 + c] = acc;
}

// ---------------- global mean pool (batch is sorted) ----------------
__device__ inline int lower_bound(const int* a, int n, int v) {
  int lo = 0, hi = n;
  while (lo < hi) {
    int m = (lo + hi) >> 1;
    if (a[m] < v) lo = m + 1; else hi = m;
  }
  return lo;
}

__global__ __launch_bounds__(128) void k_pool(const float* __restrict__ H,
                                              const int* __restrict__ batch,
                                              float* __restrict__ f) {
  int g = blockIdx.x;
  int c = threadIdx.x;
  int s = lower_bound(batch, NN, g);
  int e = lower_bound(batch, NN, g + 1);
  float acc = 0.f;
  int i = s;
  for (; i + 3 < e; i += 4) {
    acc += H[(size_t)i * 128 + c] + H[(size_t)(i + 1) * 128 + c] +
           H[(size_t)(i + 2) * 128 + c] + H[(size_t)(i + 3) * 128 + c];
  }
  for (; i < e; ++i) acc += H[(size_t)i * 128 + c];
  f[g * 128 + c] = acc / fmaxf((float)(e - s), 1.0f);
}

// ---------------- MLP head: one block per graph ----------------
__global__ __launch_bounds__(512) void k_mlp(const float* __restrict__ f,
    const float* __restrict__ W1, const float* __restrict__ b1,
    const float* __restrict__ W2, const float* __restrict__ b2,
    const float* __restrict__ W3, const float* __restrict__ b3,
    const float* __restrict__ W4, const float* __restrict__ b4,
    float* __restrict__ z) {
  __shared__ float s0[128];
  __shared__ float s1[512];
  __shared__ float s2[256];
  __shared__ float s3[128];
  int g = blockIdx.x;
  int t = threadIdx.x;
  if (t < 128) s0[t] = f[g * 128 + t];
  __syncthreads();
  {
    float a = b1[t];
#pragma unroll 4
    for (int k = 0; k < 128; ++k) a += s0[k] * W1[k * 512 + t];
    s1[t] = fmaxf(a, 0.f);
  }
  __syncthreads();
  if (t < 256) {
    float a = b2[t];
#pragma unroll 4
    for (int k = 0; k < 512; ++k) a += s1[k] * W2[k * 256 + t];
    s2[t] = fmaxf(a, 0.f);
  }
  __syncthreads();
  if (t < 128) {
    float a = b3[t];
#pragma unroll 4
    for (int k = 0; k < 256; ++k) a += s2[k] * W3[k * 128 + t];
    s3[t] = fmaxf(a, 0.f);
  }
  __syncthreads();
  if (t < 64) {
    float a = b4[t];
#pragma unroll 4
    for (int k = 0; k < 128; ++k) a += s3[k] * W4[k * 64 + t];
    z[g * 64 + t] = a;
  }
}

extern "C" void kernel_launch(void* const* d_in, const int* in_sizes, int n_in,
                              void* d_out, int out_size, void* d_ws, size_t ws_size,
                              hipStream_t stream) {
  const float* x    = (const float*)d_in[0];
  const int* ei     = (const int*)d_in[1];
  const int* batch  = (const int*)d_in[2];
  const float* W1   = (const float*)d_in[3];  const float* b1  = (const float*)d_in[4];
  const float* W2   = (const float*)d_in[5];  const float* b2  = (const float*)d_in[6];
  const float* W3   = (const float*)d_in[7];  const float* b3  = (const float*)d_in[8];
  const float* Wf1  = (const float*)d_in[9];  const float* bf1 = (const float*)d_in[10];
  const float* Wf2  = (const float*)d_in[11]; const float* bf2 = (const float*)d_in[12];
  const float* Wf3  = (const float*)d_in[13]; const float* bf3 = (const float*)d_in[14];
  const float* Wf4  = (const float*)d_in[15]; const float* bf4 = (const float*)d_in[16];
  const int* src = ei;
  const int* dst = ei + NE;

  char* ws = (char*)d_ws;
  size_t off = 0;
  auto alloc = [&](size_t bytes) {
    void* p = ws + off;
    off += (bytes + 255) & ~(size_t)255;
    return p;
  };
  float* hA      = (float*)alloc((size_t)NN * 128 * 4);
  float* hB      = (float*)alloc((size_t)NN * 128 * 4);
  float* dinv    = (float*)alloc((size_t)NN * 4);
  int*   cnt     = (int*)alloc((size_t)NN * 4);
  int*   offsets = (int*)alloc((size_t)(NN + 1) * 4);
  int*   cursor  = (int*)alloc((size_t)NN * 4);
  int*   srcs    = (int*)alloc((size_t)NE * 4);

  float* f_out = (float*)d_out;                 // [512*128]
  float* z_out = (float*)d_out + NG * HID;      // [512*64]

  hipMemsetAsync(cnt, 0, (size_t)NN * 4, stream);
  k_count<<<(NE + 255) / 256, 256, 0, stream>>>(dst, cnt);
  k_scan<<<1, 1024, 0, stream>>>(cnt, offsets, cursor, dinv);
  k_bucket<<<(NE + 255) / 256, 256, 0, stream>>>(src, dst, cursor, srcs);

  int gemm_grid = (NN + 127) / 128;
  int agg_grid = (NN + 7) / 8;

  // layer 1
  k_gemm<<<gemm_grid, 256, 0, stream>>>(x, W1, hA);
  k_agg<<<agg_grid, 256, 0, stream>>>((const float4*)hA, (const float4*)b1, dinv, offsets, srcs, (float4*)hB, 1);
  // layer 2
  k_gemm<<<gemm_grid, 256, 0, stream>>>(hB, W2, hA);
  k_agg<<<agg_grid, 256, 0, stream>>>((const float4*)hA, (const float4*)b2, dinv, offsets, srcs, (float4*)hB, 1);
  // layer 3
  k_gemm<<<gemm_grid, 256, 0, stream>>>(hB, W3, hA);
  k_agg<<<agg_grid, 256, 0, stream>>>((const float4*)hA, (const float4*)b3, dinv, offsets, srcs, (float4*)hB, 0);

  k_pool<<<NG, 128, 0, stream>>>(hB, batch, f_out);
  k_mlp<<<NG, 512, 0, stream>>>(f_out, Wf1, bf1, Wf2, bf2, Wf3, bf3, Wf4, bf4, z_out);
}

// Round 3
// 545.782 us; speedup vs baseline: 2.3363x; 1.8544x over previous
//
#include <hip/hip_runtime.h>
#include <hip/hip_bf16.h>

#define NN 100000
#define NE 1600000
#define NG 512
#define HID 128
#define NBLK 98  // ceil(NN/1024)

typedef __attribute__((ext_vector_type(8))) short short8;
typedef __attribute__((ext_vector_type(4))) float floatx4;

__device__ inline ushort f2bf(float f) {
  uint u = __float_as_uint(f);
  u += 0x7fff + ((u >> 16) & 1);
  return (ushort)(u >> 16);
}
__device__ inline uint pack2(float lo, float hi) {
  return (uint)f2bf(lo) | ((uint)f2bf(hi) << 16);
}
__device__ inline float bflo(uint u) { return __uint_as_float(u << 16); }
__device__ inline float bfhi(uint u) { return __uint_as_float(u & 0xffff0000u); }

// ---------------- degree count (in-degree by dst) ----------------
__global__ void k_count(const int* __restrict__ dst, int* __restrict__ cnt) {
  int e = blockIdx.x * 256 + threadIdx.x;
  if (e < NE) atomicAdd(&cnt[dst[e]], 1);
}

// ---------------- multi-block scan ----------------
__global__ __launch_bounds__(1024) void k_scan1(const int* __restrict__ cnt,
                                                int* __restrict__ offs,
                                                int* __restrict__ bsum) {
  __shared__ int wsum[16];
  int t = threadIdx.x, lane = t & 63, wid = t >> 6;
  int i = blockIdx.x * 1024 + t;
  int v = (i < NN) ? cnt[i] : 0;
  int iv = v;
  for (int o = 1; o < 64; o <<= 1) {
    int n = __shfl_up(iv, o, 64);
    if (lane >= o) iv += n;
  }
  if (lane == 63) wsum[wid] = iv;
  __syncthreads();
  if (wid == 0 && lane < 16) {
    int w = wsum[lane];
    for (int o = 1; o < 16; o <<= 1) {
      int n = __shfl_up(w, o, 64);
      if (lane >= o) w += n;
    }
    wsum[lane] = w;
  }
  __syncthreads();
  int excl = iv - v + (wid ? wsum[wid - 1] : 0);
  if (i < NN) offs[i] = excl;
  if (t == 0) bsum[blockIdx.x] = wsum[15];
}

__global__ void k_scan2(int* __restrict__ bsum) {
  if (threadIdx.x == 0) {
    int run = 0;
    for (int b = 0; b < NBLK; ++b) {
      int v = bsum[b];
      bsum[b] = run;
      run += v;
    }
    bsum[NBLK] = run;
  }
}

__global__ __launch_bounds__(1024) void k_scan3(const int* __restrict__ cnt,
                                                int* __restrict__ offs,
                                                const int* __restrict__ bsum,
                                                int* __restrict__ cursor,
                                                float* __restrict__ dinv) {
  int i = blockIdx.x * 1024 + threadIdx.x;
  if (i < NN) {
    int o = offs[i] + bsum[blockIdx.x];
    offs[i] = o;
    cursor[i] = o;
    dinv[i] = 1.0f / sqrtf((float)(cnt[i] + 1));
  }
  if (i == NN - 1) offs[NN] = bsum[NBLK];
}

// ---------------- bucket edges by dst ----------------
__global__ void k_bucket(const int* __restrict__ src, const int* __restrict__ dst,
                         int* __restrict__ cursor, int* __restrict__ srcs) {
  int e = blockIdx.x * 256 + threadIdx.x;
  if (e < NE) {
    int p = atomicAdd(&cursor[dst[e]], 1);
    srcs[p] = src[e];
  }
}

// ---------------- cast x f32 -> bf16 ----------------
__global__ void k_cast(const float4* __restrict__ x, uint2* __restrict__ xb, int n4) {
  int i = blockIdx.x * 256 + threadIdx.x;
  if (i < n4) {
    float4 v = x[i];
    uint2 o;
    o.x = pack2(v.x, v.y);
    o.y = pack2(v.z, v.w);
    xb[i] = o;
  }
}

// ---------------- prep W: f32 [128,128] -> bf16 W^T swizzled ----------------
// wt[c*128 + ((k>>3)^(c&15))*8 + (k&7)] = bf16(W[k][c])
__global__ __launch_bounds__(128) void k_prepW(const float* __restrict__ W,
                                               ushort* __restrict__ wt) {
  int c = blockIdx.x;
  int r = threadIdx.x;
  float v = W[r * 128 + c];
  wt[c * 128 + (((r >> 3) ^ (c & 15)) << 3) + (r & 7)] = f2bf(v);
}

// ---------------- bf16 MFMA GEMM: H[N,128] = X[N,128] @ W ----------------
// 256 threads = 4 waves; each wave: 16 rows x 128 cols. BM=64/block.
__global__ __launch_bounds__(256) void k_gemm(const ushort* __restrict__ Xb,
                                              const ushort* __restrict__ wt,
                                              ushort* __restrict__ Hb) {
  __shared__ ushort sW[128 * 128];
  int t = threadIdx.x;
#pragma unroll
  for (int l = 0; l < 8; ++l) {
    int idx = t + l * 256;
    ((uint4*)sW)[idx] = ((const uint4*)wt)[idx];
  }
  __syncthreads();
  int wid = t >> 6, lane = t & 63;
  int row0 = blockIdx.x * 64 + wid * 16;
  int arow = row0 + (lane & 15);
  if (arow >= NN) arow = NN - 1;  // clamp; stores masked below
  const ushort* aptr = Xb + (size_t)arow * 128 + ((lane >> 4) * 8);
  floatx4 acc[8];
#pragma unroll
  for (int n = 0; n < 8; ++n) acc[n] = (floatx4)(0.f);
#pragma unroll
  for (int kb = 0; kb < 4; ++kb) {
    short8 a = *(const short8*)(aptr + kb * 32);
    int kslot = kb * 4 + (lane >> 4);
#pragma unroll
    for (int n = 0; n < 8; ++n) {
      int col = n * 16 + (lane & 15);
      const ushort* bp = sW + col * 128 + ((kslot ^ (col & 15)) << 3);
      short8 b = *(const short8*)bp;
      acc[n] = __builtin_amdgcn_mfma_f32_16x16x32_bf16(a, b, acc[n], 0, 0, 0);
    }
  }
  int srow_base = row0 + (lane >> 4) * 4;
#pragma unroll
  for (int r = 0; r < 4; ++r) {
    int grow = srow_base + r;
    if (grow < NN) {
      ushort* out = Hb + (size_t)grow * 128 + (lane & 15);
#pragma unroll
      for (int n = 0; n < 8; ++n) out[n * 16] = f2bf(acc[n][r]);
    }
  }
}

// ---------------- pull-mode aggregation on bf16 rows ----------------
// 16-lane group per node (16B = 8 bf16 channels per lane), 16 nodes/block.
__global__ __launch_bounds__(256) void k_agg(const ushort* __restrict__ H,
                                             const float* __restrict__ bias,
                                             const float* __restrict__ dinv,
                                             const int* __restrict__ offsets,
                                             const int* __restrict__ srcs,
                                             ushort* __restrict__ Hout, int do_relu) {
  int node = blockIdx.x * 16 + (threadIdx.x >> 4);
  if (node >= NN) return;
  int c8 = threadIdx.x & 15;  // 16B slot; channels c8*8 .. c8*8+7
  float di = dinv[node];
  int s = offsets[node], e = offsets[node + 1];
  float acc[8];
#pragma unroll
  for (int j = 0; j < 8; ++j) acc[j] = 0.f;
  int i = s;
  for (; i + 3 < e; i += 4) {
    int s0 = srcs[i], s1 = srcs[i + 1], s2 = srcs[i + 2], s3 = srcs[i + 3];
    float d0 = dinv[s0], d1 = dinv[s1], d2 = dinv[s2], d3 = dinv[s3];
    uint4 v0 = *((const uint4*)(H + (size_t)s0 * 128) + c8);
    uint4 v1 = *((const uint4*)(H + (size_t)s1 * 128) + c8);
    uint4 v2 = *((const uint4*)(H + (size_t)s2 * 128) + c8);
    uint4 v3 = *((const uint4*)(H + (size_t)s3 * 128) + c8);
    acc[0] += bflo(v0.x) * d0 + bflo(v1.x) * d1 + bflo(v2.x) * d2 + bflo(v3.x) * d3;
    acc[1] += bfhi(v0.x) * d0 + bfhi(v1.x) * d1 + bfhi(v2.x) * d2 + bfhi(v3.x) * d3;
    acc[2] += bflo(v0.y) * d0 + bflo(v1.y) * d1 + bflo(v2.y) * d2 + bflo(v3.y) * d3;
    acc[3] += bfhi(v0.y) * d0 + bfhi(v1.y) * d1 + bfhi(v2.y) * d2 + bfhi(v3.y) * d3;
    acc[4] += bflo(v0.z) * d0 + bflo(v1.z) * d1 + bflo(v2.z) * d2 + bflo(v3.z) * d3;
    acc[5] += bfhi(v0.z) * d0 + bfhi(v1.z) * d1 + bfhi(v2.z) * d2 + bfhi(v3.z) * d3;
    acc[6] += bflo(v0.w) * d0 + bflo(v1.w) * d1 + bflo(v2.w) * d2 + bflo(v3.w) * d3;
    acc[7] += bfhi(v0.w) * d0 + bfhi(v1.w) * d1 + bfhi(v2.w) * d2 + bfhi(v3.w) * d3;
  }
  for (; i < e; ++i) {
    int s0 = srcs[i];
    float d0 = dinv[s0];
    uint4 v0 = *((const uint4*)(H + (size_t)s0 * 128) + c8);
    acc[0] += bflo(v0.x) * d0;
    acc[1] += bfhi(v0.x) * d0;
    acc[2] += bflo(v0.y) * d0;
    acc[3] += bfhi(v0.y) * d0;
    acc[4] += bflo(v0.z) * d0;
    acc[5] += bfhi(v0.z) * d0;
    acc[6] += bflo(v0.w) * d0;
    acc[7] += bfhi(v0.w) * d0;
  }
  uint4 hv = *((const uint4*)(H + (size_t)node * 128) + c8);
  float hb[8] = {bflo(hv.x), bfhi(hv.x), bflo(hv.y), bfhi(hv.y),
                 bflo(hv.z), bfhi(hv.z), bflo(hv.w), bfhi(hv.w)};
  float dii = di * di;
  const float* bp = bias + c8 * 8;
  float r[8];
#pragma unroll
  for (int j = 0; j < 8; ++j) {
    float v = acc[j] * di + hb[j] * dii + bp[j];
    if (do_relu) v = fmaxf(v, 0.f);
    r[j] = v;
  }
  uint4 o;
  o.x = pack2(r[0], r[1]);
  o.y = pack2(r[2], r[3]);
  o.z = pack2(r[4], r[5]);
  o.w = pack2(r[6], r[7]);
  *((uint4*)(Hout + (size_t)node * 128) + c8) = o;
}

// ---------------- global mean pool (batch is sorted), bf16 in ----------------
__device__ inline int lower_bound(const int* a, int n, int v) {
  int lo = 0, hi = n;
  while (lo < hi) {
    int m = (lo + hi) >> 1;
    if (a[m] < v) lo = m + 1; else hi = m;
  }
  return lo;
}

__global__ __launch_bounds__(128) void k_pool(const ushort* __restrict__ H,
                                              const int* __restrict__ batch,
                                              float* __restrict__ f) {
  int g = blockIdx.x;
  int c = threadIdx.x;
  int s = lower_bound(batch, NN, g);
  int e = lower_bound(batch, NN, g + 1);
  float acc = 0.f;
#pragma unroll 4
  for (int i = s; i < e; ++i)
    acc += __uint_as_float(((uint)H[(size_t)i * 128 + c]) << 16);
  f[g * 128 + c] = acc / fmaxf((float)(e - s), 1.0f);
}

// ---------------- MLP head: one block per graph ----------------
__global__ __launch_bounds__(512) void k_mlp(const float* __restrict__ f,
    const float* __restrict__ W1, const float* __restrict__ b1,
    const float* __restrict__ W2, const float* __restrict__ b2,
    const float* __restrict__ W3, const float* __restrict__ b3,
    const float* __restrict__ W4, const float* __restrict__ b4,
    float* __restrict__ z) {
  __shared__ float s0[128];
  __shared__ float s1[512];
  __shared__ float s2[256];
  __shared__ float s3[128];
  int g = blockIdx.x;
  int t = threadIdx.x;
  if (t < 128) s0[t] = f[g * 128 + t];
  __syncthreads();
  {
    float a = b1[t];
#pragma unroll 4
    for (int k = 0; k < 128; ++k) a += s0[k] * W1[k * 512 + t];
    s1[t] = fmaxf(a, 0.f);
  }
  __syncthreads();
  if (t < 256) {
    float a = b2[t];
#pragma unroll 4
    for (int k = 0; k < 512; ++k) a += s1[k] * W2[k * 256 + t];
    s2[t] = fmaxf(a, 0.f);
  }
  __syncthreads();
  if (t < 128) {
    float a = b3[t];
#pragma unroll 4
    for (int k = 0; k < 256; ++k) a += s2[k] * W3[k * 128 + t];
    s3[t] = fmaxf(a, 0.f);
  }
  __syncthreads();
  if (t < 64) {
    float a = b4[t];
#pragma unroll 4
    for (int k = 0; k < 128; ++k) a += s3[k] * W4[k * 64 + t];
    z[g * 64 + t] = a;
  }
}

extern "C" void kernel_launch(void* const* d_in, const int* in_sizes, int n_in,
                              void* d_out, int out_size, void* d_ws, size_t ws_size,
                              hipStream_t stream) {
  const float* x    = (const float*)d_in[0];
  const int* ei     = (const int*)d_in[1];
  const int* batch  = (const int*)d_in[2];
  const float* W1   = (const float*)d_in[3];  const float* b1  = (const float*)d_in[4];
  const float* W2   = (const float*)d_in[5];  const float* b2  = (const float*)d_in[6];
  const float* W3   = (const float*)d_in[7];  const float* b3  = (const float*)d_in[8];
  const float* Wf1  = (const float*)d_in[9];  const float* bf1 = (const float*)d_in[10];
  const float* Wf2  = (const float*)d_in[11]; const float* bf2 = (const float*)d_in[12];
  const float* Wf3  = (const float*)d_in[13]; const float* bf3 = (const float*)d_in[14];
  const float* Wf4  = (const float*)d_in[15]; const float* bf4 = (const float*)d_in[16];
  const int* src = ei;
  const int* dst = ei + NE;

  char* ws = (char*)d_ws;
  size_t off = 0;
  auto alloc = [&](size_t bytes) {
    void* p = ws + off;
    off += (bytes + 255) & ~(size_t)255;
    return p;
  };
  ushort* B0     = (ushort*)alloc((size_t)NN * 128 * 2);
  ushort* B1     = (ushort*)alloc((size_t)NN * 128 * 2);
  ushort* B2     = (ushort*)alloc((size_t)NN * 128 * 2);
  float* dinv    = (float*)alloc((size_t)NN * 4);
  int*   cnt     = (int*)alloc((size_t)NN * 4);
  int*   offsets = (int*)alloc((size_t)(NN + 1) * 4);
  int*   cursor  = (int*)alloc((size_t)NN * 4);
  int*   srcs    = (int*)alloc((size_t)NE * 4);
  int*   bsum    = (int*)alloc((size_t)(NBLK + 1) * 4);
  ushort* wt1    = (ushort*)alloc(128 * 128 * 2);
  ushort* wt2    = (ushort*)alloc(128 * 128 * 2);
  ushort* wt3    = (ushort*)alloc(128 * 128 * 2);

  float* f_out = (float*)d_out;             // [512*128]
  float* z_out = (float*)d_out + NG * HID;  // [512*64]

  hipMemsetAsync(cnt, 0, (size_t)NN * 4, stream);
  k_count<<<(NE + 255) / 256, 256, 0, stream>>>(dst, cnt);
  k_scan1<<<NBLK, 1024, 0, stream>>>(cnt, offsets, bsum);
  k_scan2<<<1, 64, 0, stream>>>(bsum);
  k_scan3<<<NBLK, 1024, 0, stream>>>(cnt, offsets, bsum, cursor, dinv);
  k_bucket<<<(NE + 255) / 256, 256, 0, stream>>>(src, dst, cursor, srcs);

  k_prepW<<<128, 128, 0, stream>>>(W1, wt1);
  k_prepW<<<128, 128, 0, stream>>>(W2, wt2);
  k_prepW<<<128, 128, 0, stream>>>(W3, wt3);
  k_cast<<<(NN * 128 / 4 + 255) / 256, 256, 0, stream>>>((const float4*)x, (uint2*)B0, NN * 128 / 4);

  int gemm_grid = (NN + 63) / 64;
  int agg_grid = (NN + 15) / 16;

  // layer 1
  k_gemm<<<gemm_grid, 256, 0, stream>>>(B0, wt1, B1);
  k_agg<<<agg_grid, 256, 0, stream>>>(B1, b1, dinv, offsets, srcs, B2, 1);
  // layer 2
  k_gemm<<<gemm_grid, 256, 0, stream>>>(B2, wt2, B1);
  k_agg<<<agg_grid, 256, 0, stream>>>(B1, b2, dinv, offsets, srcs, B0, 1);
  // layer 3
  k_gemm<<<gemm_grid, 256, 0, stream>>>(B0, wt3, B1);
  k_agg<<<agg_grid, 256, 0, stream>>>(B1, b3, dinv, offsets, srcs, B2, 0);

  k_pool<<<NG, 128, 0, stream>>>(B2, batch, f_out);
  k_mlp<<<NG, 512, 0, stream>>>(f_out, Wf1, bf1, Wf2, bf2, Wf3, bf3, Wf4, bf4, z_out);
}

// Round 6
// 474.892 us; speedup vs baseline: 2.6850x; 1.1493x over previous
//
#include <hip/hip_runtime.h>
#include <hip/hip_bf16.h>

#define NN 100000
#define NE 1600000
#define NG 512
#define HID 128
#define NBLK 98    // ceil(NN/1024)
#define PPART 391  // ceil(NN/256) partitions of 256 nodes
#define EPB 4096   // edges per block in k_part

typedef __attribute__((ext_vector_type(8))) short short8;
typedef __attribute__((ext_vector_type(4))) float floatx4;

__device__ inline ushort f2bf(float f) {
  uint u = __float_as_uint(f);
  u += 0x7fff + ((u >> 16) & 1);
  return (ushort)(u >> 16);
}
__device__ inline uint pack2(float lo, float hi) {
  return (uint)f2bf(lo) | ((uint)f2bf(hi) << 16);
}
__device__ inline float bflo(uint u) { return __uint_as_float(u << 16); }
__device__ inline float bfhi(uint u) { return __uint_as_float(u & 0xffff0000u); }

// ---------------- degree count (in-degree by dst) ----------------
__global__ void k_count(const int* __restrict__ dst, int* __restrict__ cnt) {
  int e = blockIdx.x * 256 + threadIdx.x;
  if (e < NE) atomicAdd(&cnt[dst[e]], 1);
}

// ---------------- multi-block scan ----------------
__global__ __launch_bounds__(1024) void k_scan1(const int* __restrict__ cnt,
                                                int* __restrict__ offs,
                                                int* __restrict__ bsum) {
  __shared__ int wsum[16];
  int t = threadIdx.x, lane = t & 63, wid = t >> 6;
  int i = blockIdx.x * 1024 + t;
  int v = (i < NN) ? cnt[i] : 0;
  int iv = v;
  for (int o = 1; o < 64; o <<= 1) {
    int n = __shfl_up(iv, o, 64);
    if (lane >= o) iv += n;
  }
  if (lane == 63) wsum[wid] = iv;
  __syncthreads();
  if (wid == 0 && lane < 16) {
    int w = wsum[lane];
    for (int o = 1; o < 16; o <<= 1) {
      int n = __shfl_up(w, o, 64);
      if (lane >= o) w += n;
    }
    wsum[lane] = w;
  }
  __syncthreads();
  int excl = iv - v + (wid ? wsum[wid - 1] : 0);
  if (i < NN) offs[i] = excl;
  if (t == 0) bsum[blockIdx.x] = wsum[15];
}

__global__ void k_scan2(int* __restrict__ bsum) {
  if (threadIdx.x == 0) {
    int run = 0;
    for (int b = 0; b < NBLK; ++b) {
      int v = bsum[b];
      bsum[b] = run;
      run += v;
    }
    bsum[NBLK] = run;
  }
}

__global__ __launch_bounds__(1024) void k_scan3(const int* __restrict__ cnt,
                                                int* __restrict__ offs,
                                                const int* __restrict__ bsum,
                                                float* __restrict__ dinv) {
  int i = blockIdx.x * 1024 + threadIdx.x;
  if (i < NN) {
    int o = offs[i] + bsum[blockIdx.x];
    offs[i] = o;
    dinv[i] = 1.0f / sqrtf((float)(cnt[i] + 1));
  }
  if (i == NN - 1) offs[NN] = bsum[NBLK];
}

// ---------------- partition cursor init: pcur[p] = offsets[p*256] ----------------
__global__ void k_pinit(const int* __restrict__ offsets, int* __restrict__ pcur) {
  int p = blockIdx.x * 256 + threadIdx.x;
  if (p < PPART) pcur[p] = offsets[p << 8];
}

// ---------------- phase A: scatter packed edges into partition regions ----------------
__global__ __launch_bounds__(256) void k_part(const int* __restrict__ src,
                                              const int* __restrict__ dst,
                                              int* __restrict__ pcur,
                                              uint* __restrict__ pedge) {
  __shared__ int hist[PPART];
  __shared__ int base[PPART];
  int t = threadIdx.x;
  for (int i = t; i < PPART; i += 256) hist[i] = 0;
  __syncthreads();
  int e0 = blockIdx.x * EPB;
  int d_[16];
#pragma unroll
  for (int l = 0; l < 16; ++l) {
    int e = e0 + l * 256 + t;
    if (e < NE) {
      int d = dst[e];
      d_[l] = d;
      atomicAdd(&hist[d >> 8], 1);
    } else {
      d_[l] = -1;
    }
  }
  __syncthreads();
  for (int i = t; i < PPART; i += 256) {
    int h = hist[i];
    base[i] = h ? atomicAdd(&pcur[i], h) : 0;
  }
  __syncthreads();
#pragma unroll
  for (int l = 0; l < 16; ++l) {
    int e = e0 + l * 256 + t;
    if (e < NE) {
      int d = d_[l];
      int s = src[e];
      int pos = atomicAdd(&base[d >> 8], 1);
      pedge[pos] = (uint)s | ((uint)(d & 255) << 24);
    }
  }
}

// ---------------- phase B: exact bucket within each partition ----------------
__global__ __launch_bounds__(256) void k_bucket2(const int* __restrict__ offsets,
                                                 const uint* __restrict__ pedge,
                                                 int* __restrict__ srcs) {
  __shared__ int cur[256];
  int p = blockIdx.x;
  int n0 = p << 8;
  int t = threadIdx.x;
  int hi = n0 + 256; if (hi > NN) hi = NN;
  if (n0 + t < hi) cur[t] = offsets[n0 + t];
  __syncthreads();
  int s = offsets[n0];
  int e = offsets[hi];
  for (int i = s + t; i < e; i += 256) {
    uint v = pedge[i];
    int pos = atomicAdd(&cur[v >> 24], 1);
    srcs[pos] = (int)(v & 0xFFFFFFu);
  }
}

// ---------------- cast x f32 -> bf16 ----------------
__global__ void k_cast(const float4* __restrict__ x, uint2* __restrict__ xb, int n4) {
  int i = blockIdx.x * 256 + threadIdx.x;
  if (i < n4) {
    float4 v = x[i];
    uint2 o;
    o.x = pack2(v.x, v.y);
    o.y = pack2(v.z, v.w);
    xb[i] = o;
  }
}

// ---------------- prep W: f32 [128,128] -> bf16 W^T swizzled ----------------
// wt[c*128 + ((k>>3)^(c&15))*8 + (k&7)] = bf16(W[k][c])
__global__ __launch_bounds__(128) void k_prepW(const float* __restrict__ W,
                                               ushort* __restrict__ wt) {
  int c = blockIdx.x;
  int r = threadIdx.x;
  float v = W[r * 128 + c];
  wt[c * 128 + (((r >> 3) ^ (c & 15)) << 3) + (r & 7)] = f2bf(v);
}

// ---------------- bf16 MFMA GEMM: H[N,128] = X[N,128] @ W ----------------
// 256 threads = 4 waves; each wave: 16 rows x 128 cols. BM=64/block.
__global__ __launch_bounds__(256) void k_gemm(const ushort* __restrict__ Xb,
                                              const ushort* __restrict__ wt,
                                              ushort* __restrict__ Hb) {
  __shared__ ushort sW[128 * 128];
  int t = threadIdx.x;
#pragma unroll
  for (int l = 0; l < 8; ++l) {
    int idx = t + l * 256;
    ((uint4*)sW)[idx] = ((const uint4*)wt)[idx];
  }
  __syncthreads();
  int wid = t >> 6, lane = t & 63;
  int row0 = blockIdx.x * 64 + wid * 16;
  int arow = row0 + (lane & 15);
  if (arow >= NN) arow = NN - 1;  // clamp; stores masked below
  const ushort* aptr = Xb + (size_t)arow * 128 + ((lane >> 4) * 8);
  floatx4 acc[8];
#pragma unroll
  for (int n = 0; n < 8; ++n) acc[n] = (floatx4)(0.f);
#pragma unroll
  for (int kb = 0; kb < 4; ++kb) {
    short8 a = *(const short8*)(aptr + kb * 32);
    int kslot = kb * 4 + (lane >> 4);
#pragma unroll
    for (int n = 0; n < 8; ++n) {
      int col = n * 16 + (lane & 15);
      const ushort* bp = sW + col * 128 + ((kslot ^ (col & 15)) << 3);
      short8 b = *(const short8*)bp;
      acc[n] = __builtin_amdgcn_mfma_f32_16x16x32_bf16(a, b, acc[n], 0, 0, 0);
    }
  }
  int srow_base = row0 + (lane >> 4) * 4;
#pragma unroll
  for (int r = 0; r < 4; ++r) {
    int grow = srow_base + r;
    if (grow < NN) {
      ushort* out = Hb + (size_t)grow * 128 + (lane & 15);
#pragma unroll
      for (int n = 0; n < 8; ++n) out[n * 16] = f2bf(acc[n][r]);
    }
  }
}

// ---------------- pull-mode aggregation on bf16 rows, 8-edge unroll ----------------
// 16-lane group per node (16B = 8 bf16 channels per lane), 16 nodes/block.
__global__ __launch_bounds__(256) void k_agg(const ushort* __restrict__ H,
                                             const float* __restrict__ bias,
                                             const float* __restrict__ dinv,
                                             const int* __restrict__ offsets,
                                             const int* __restrict__ srcs,
                                             ushort* __restrict__ Hout, int do_relu) {
  int node = blockIdx.x * 16 + (threadIdx.x >> 4);
  if (node >= NN) return;
  int c8 = threadIdx.x & 15;  // 16B slot; channels c8*8 .. c8*8+7
  float di = dinv[node];
  int s = offsets[node], e = offsets[node + 1];
  float acc[8];
#pragma unroll
  for (int j = 0; j < 8; ++j) acc[j] = 0.f;
  int i = s;
  for (; i + 7 < e; i += 8) {
    int sx[8];
    float dx[8];
    uint4 vx[8];
#pragma unroll
    for (int u = 0; u < 8; ++u) sx[u] = srcs[i + u];
#pragma unroll
    for (int u = 0; u < 8; ++u) dx[u] = dinv[sx[u]];
#pragma unroll
    for (int u = 0; u < 8; ++u) vx[u] = *((const uint4*)(H + (size_t)sx[u] * 128) + c8);
#pragma unroll
    for (int u = 0; u < 8; ++u) {
      acc[0] += bflo(vx[u].x) * dx[u];
      acc[1] += bfhi(vx[u].x) * dx[u];
      acc[2] += bflo(vx[u].y) * dx[u];
      acc[3] += bfhi(vx[u].y) * dx[u];
      acc[4] += bflo(vx[u].z) * dx[u];
      acc[5] += bfhi(vx[u].z) * dx[u];
      acc[6] += bflo(vx[u].w) * dx[u];
      acc[7] += bfhi(vx[u].w) * dx[u];
    }
  }
  for (; i < e; ++i) {
    int s0 = srcs[i];
    float d0 = dinv[s0];
    uint4 v0 = *((const uint4*)(H + (size_t)s0 * 128) + c8);
    acc[0] += bflo(v0.x) * d0;
    acc[1] += bfhi(v0.x) * d0;
    acc[2] += bflo(v0.y) * d0;
    acc[3] += bfhi(v0.y) * d0;
    acc[4] += bflo(v0.z) * d0;
    acc[5] += bfhi(v0.z) * d0;
    acc[6] += bflo(v0.w) * d0;
    acc[7] += bfhi(v0.w) * d0;
  }
  uint4 hv = *((const uint4*)(H + (size_t)node * 128) + c8);
  float hb[8] = {bflo(hv.x), bfhi(hv.x), bflo(hv.y), bfhi(hv.y),
                 bflo(hv.z), bfhi(hv.z), bflo(hv.w), bfhi(hv.w)};
  float dii = di * di;
  const float* bp = bias + c8 * 8;
  float r[8];
#pragma unroll
  for (int j = 0; j < 8; ++j) {
    float v = acc[j] * di + hb[j] * dii + bp[j];
    if (do_relu) v = fmaxf(v, 0.f);
    r[j] = v;
  }
  uint4 o;
  o.x = pack2(r[0], r[1]);
  o.y = pack2(r[2], r[3]);
  o.z = pack2(r[4], r[5]);
  o.w = pack2(r[6], r[7]);
  *((uint4*)(Hout + (size_t)node * 128) + c8) = o;
}

// ---------------- global mean pool (batch is sorted), bf16 in ----------------
__device__ inline int lower_bound(const int* a, int n, int v) {
  int lo = 0, hi = n;
  while (lo < hi) {
    int m = (lo + hi) >> 1;
    if (a[m] < v) lo = m + 1; else hi = m;
  }
  return lo;
}

__global__ __launch_bounds__(128) void k_pool(const ushort* __restrict__ H,
                                              const int* __restrict__ batch,
                                              float* __restrict__ f) {
  int g = blockIdx.x;
  int c = threadIdx.x;
  int s = lower_bound(batch, NN, g);
  int e = lower_bound(batch, NN, g + 1);
  float acc = 0.f;
#pragma unroll 4
  for (int i = s; i < e; ++i)
    acc += __uint_as_float(((uint)H[(size_t)i * 128 + c]) << 16);
  f[g * 128 + c] = acc / fmaxf((float)(e - s), 1.0f);
}

// ---------------- MLP head: one block per graph ----------------
__global__ __launch_bounds__(512) void k_mlp(const float* __restrict__ f,
    const float* __restrict__ W1, const float* __restrict__ b1,
    const float* __restrict__ W2, const float* __restrict__ b2,
    const float* __restrict__ W3, const float* __restrict__ b3,
    const float* __restrict__ W4, const float* __restrict__ b4,
    float* __restrict__ z) {
  __shared__ float s0[128];
  __shared__ float s1[512];
  __shared__ float s2[256];
  __shared__ float s3[128];
  int g = blockIdx.x;
  int t = threadIdx.x;
  if (t < 128) s0[t] = f[g * 128 + t];
  __syncthreads();
  {
    float a = b1[t];
#pragma unroll 4
    for (int k = 0; k < 128; ++k) a += s0[k] * W1[k * 512 + t];
    s1[t] = fmaxf(a, 0.f);
  }
  __syncthreads();
  if (t < 256) {
    float a = b2[t];
#pragma unroll 4
    for (int k = 0; k < 512; ++k) a += s1[k] * W2[k * 256 + t];
    s2[t] = fmaxf(a, 0.f);
  }
  __syncthreads();
  if (t < 128) {
    float a = b3[t];
#pragma unroll 4
    for (int k = 0; k < 256; ++k) a += s2[k] * W3[k * 128 + t];
    s3[t] = fmaxf(a, 0.f);
  }
  __syncthreads();
  if (t < 64) {
    float a = b4[t];
#pragma unroll 4
    for (int k = 0; k < 128; ++k) a += s3[k] * W4[k * 64 + t];
    z[g * 64 + t] = a;
  }
}

extern "C" void kernel_launch(void* const* d_in, const int* in_sizes, int n_in,
                              void* d_out, int out_size, void* d_ws, size_t ws_size,
                              hipStream_t stream) {
  const float* x    = (const float*)d_in[0];
  const int* ei     = (const int*)d_in[1];
  const int* batch  = (const int*)d_in[2];
  const float* W1   = (const float*)d_in[3];  const float* b1  = (const float*)d_in[4];
  const float* W2   = (const float*)d_in[5];  const float* b2  = (const float*)d_in[6];
  const float* W3   = (const float*)d_in[7];  const float* b3  = (const float*)d_in[8];
  const float* Wf1  = (const float*)d_in[9];  const float* bf1 = (const float*)d_in[10];
  const float* Wf2  = (const float*)d_in[11]; const float* bf2 = (const float*)d_in[12];
  const float* Wf3  = (const float*)d_in[13]; const float* bf3 = (const float*)d_in[14];
  const float* Wf4  = (const float*)d_in[15]; const float* bf4 = (const float*)d_in[16];
  const int* src = ei;
  const int* dst = ei + NE;

  char* ws = (char*)d_ws;
  size_t off = 0;
  auto alloc = [&](size_t bytes) {
    void* p = ws + off;
    off += (bytes + 255) & ~(size_t)255;
    return p;
  };
  ushort* B0     = (ushort*)alloc((size_t)NN * 128 * 2);
  ushort* B1     = (ushort*)alloc((size_t)NN * 128 * 2);
  ushort* B2     = (ushort*)alloc((size_t)NN * 128 * 2);
  float* dinv    = (float*)alloc((size_t)NN * 4);
  int*   cnt     = (int*)alloc((size_t)NN * 4);
  int*   offsets = (int*)alloc((size_t)(NN + 1) * 4);
  int*   srcs    = (int*)alloc((size_t)NE * 4);
  uint*  pedge   = (uint*)alloc((size_t)NE * 4);
  int*   pcur    = (int*)alloc((size_t)PPART * 4);
  int*   bsum    = (int*)alloc((size_t)(NBLK + 1) * 4);
  ushort* wt1    = (ushort*)alloc(128 * 128 * 2);
  ushort* wt2    = (ushort*)alloc(128 * 128 * 2);
  ushort* wt3    = (ushort*)alloc(128 * 128 * 2);

  float* f_out = (float*)d_out;             // [512*128]
  float* z_out = (float*)d_out + NG * HID;  // [512*64]

  hipMemsetAsync(cnt, 0, (size_t)NN * 4, stream);
  k_count<<<(NE + 255) / 256, 256, 0, stream>>>(dst, cnt);
  k_scan1<<<NBLK, 1024, 0, stream>>>(cnt, offsets, bsum);
  k_scan2<<<1, 64, 0, stream>>>(bsum);
  k_scan3<<<NBLK, 1024, 0, stream>>>(cnt, offsets, bsum, dinv);
  k_pinit<<<(PPART + 255) / 256, 256, 0, stream>>>(offsets, pcur);
  k_part<<<(NE + EPB - 1) / EPB, 256, 0, stream>>>(src, dst, pcur, pedge);
  k_bucket2<<<PPART, 256, 0, stream>>>(offsets, pedge, srcs);

  k_prepW<<<128, 128, 0, stream>>>(W1, wt1);
  k_prepW<<<128, 128, 0, stream>>>(W2, wt2);
  k_prepW<<<128, 128, 0, stream>>>(W3, wt3);
  k_cast<<<(NN * 128 / 4 + 255) / 256, 256, 0, stream>>>((const float4*)x, (uint2*)B0, NN * 128 / 4);

  int gemm_grid = (NN + 63) / 64;
  int agg_grid = (NN + 15) / 16;

  // layer 1
  k_gemm<<<gemm_grid, 256, 0, stream>>>(B0, wt1, B1);
  k_agg<<<agg_grid, 256, 0, stream>>>(B1, b1, dinv, offsets, srcs, B2, 1);
  // layer 2
  k_gemm<<<gemm_grid, 256, 0, stream>>>(B2, wt2, B1);
  k_agg<<<agg_grid, 256, 0, stream>>>(B1, b2, dinv, offsets, srcs, B0, 1);
  // layer 3
  k_gemm<<<gemm_grid, 256, 0, stream>>>(B0, wt3, B1);
  k_agg<<<agg_grid, 256, 0, stream>>>(B1, b3, dinv, offsets, srcs, B2, 0);

  k_pool<<<NG, 128, 0, stream>>>(B2, batch, f_out);
  k_mlp<<<NG, 512, 0, stream>>>(f_out, Wf1, bf1, Wf2, bf2, Wf3, bf3, Wf4, bf4, z_out);
}

// Round 7
// 474.673 us; speedup vs baseline: 2.6863x; 1.0005x over previous
//
#include <hip/hip_runtime.h>
#include <hip/hip_bf16.h>

#define NN 100000
#define NE 1600000
#define NG 512
#define HID 128
#define NBLK 98    // ceil(NN/1024)
#define PPART 391  // ceil(NN/256) partitions of 256 nodes
#define EPB 4096   // edges per block in k_part

typedef __attribute__((ext_vector_type(8))) short short8;
typedef __attribute__((ext_vector_type(4))) float floatx4;

__device__ inline ushort f2bf(float f) {
  uint u = __float_as_uint(f);
  u += 0x7fff + ((u >> 16) & 1);
  return (ushort)(u >> 16);
}
__device__ inline uint pack2(float lo, float hi) {
  return (uint)f2bf(lo) | ((uint)f2bf(hi) << 16);
}
__device__ inline float bflo(uint u) { return __uint_as_float(u << 16); }
__device__ inline float bfhi(uint u) { return __uint_as_float(u & 0xffff0000u); }

// ---------------- degree count (in-degree by dst) ----------------
__global__ void k_count(const int* __restrict__ dst, int* __restrict__ cnt) {
  int e = blockIdx.x * 256 + threadIdx.x;
  if (e < NE) atomicAdd(&cnt[dst[e]], 1);
}

// ---------------- multi-block scan ----------------
__global__ __launch_bounds__(1024) void k_scan1(const int* __restrict__ cnt,
                                                int* __restrict__ offs,
                                                int* __restrict__ bsum) {
  __shared__ int wsum[16];
  int t = threadIdx.x, lane = t & 63, wid = t >> 6;
  int i = blockIdx.x * 1024 + t;
  int v = (i < NN) ? cnt[i] : 0;
  int iv = v;
  for (int o = 1; o < 64; o <<= 1) {
    int n = __shfl_up(iv, o, 64);
    if (lane >= o) iv += n;
  }
  if (lane == 63) wsum[wid] = iv;
  __syncthreads();
  if (wid == 0 && lane < 16) {
    int w = wsum[lane];
    for (int o = 1; o < 16; o <<= 1) {
      int n = __shfl_up(w, o, 64);
      if (lane >= o) w += n;
    }
    wsum[lane] = w;
  }
  __syncthreads();
  int excl = iv - v + (wid ? wsum[wid - 1] : 0);
  if (i < NN) offs[i] = excl;
  if (t == 0) bsum[blockIdx.x] = wsum[15];
}

__global__ void k_scan2(int* __restrict__ bsum) {
  if (threadIdx.x == 0) {
    int run = 0;
    for (int b = 0; b < NBLK; ++b) {
      int v = bsum[b];
      bsum[b] = run;
      run += v;
    }
    bsum[NBLK] = run;
  }
}

__global__ __launch_bounds__(1024) void k_scan3(const int* __restrict__ cnt,
                                                int* __restrict__ offs,
                                                const int* __restrict__ bsum,
                                                float* __restrict__ dinv) {
  int i = blockIdx.x * 1024 + threadIdx.x;
  if (i < NN) {
    int o = offs[i] + bsum[blockIdx.x];
    offs[i] = o;
    dinv[i] = 1.0f / sqrtf((float)(cnt[i] + 1));
  }
  if (i == NN - 1) offs[NN] = bsum[NBLK];
}

// ---------------- partition cursor init: pcur[p] = offsets[p*256] ----------------
__global__ void k_pinit(const int* __restrict__ offsets, int* __restrict__ pcur) {
  int p = blockIdx.x * 256 + threadIdx.x;
  if (p < PPART) pcur[p] = offsets[p << 8];
}

// ---------------- phase A: scatter packed edges into partition regions ----------------
__global__ __launch_bounds__(256) void k_part(const int* __restrict__ src,
                                              const int* __restrict__ dst,
                                              int* __restrict__ pcur,
                                              uint* __restrict__ pedge) {
  __shared__ int hist[PPART];
  __shared__ int base[PPART];
  int t = threadIdx.x;
  for (int i = t; i < PPART; i += 256) hist[i] = 0;
  __syncthreads();
  int e0 = blockIdx.x * EPB;
  int d_[16];
#pragma unroll
  for (int l = 0; l < 16; ++l) {
    int e = e0 + l * 256 + t;
    if (e < NE) {
      int d = dst[e];
      d_[l] = d;
      atomicAdd(&hist[d >> 8], 1);
    } else {
      d_[l] = -1;
    }
  }
  __syncthreads();
  for (int i = t; i < PPART; i += 256) {
    int h = hist[i];
    base[i] = h ? atomicAdd(&pcur[i], h) : 0;
  }
  __syncthreads();
#pragma unroll
  for (int l = 0; l < 16; ++l) {
    int e = e0 + l * 256 + t;
    if (e < NE) {
      int d = d_[l];
      int s = src[e];
      int pos = atomicAdd(&base[d >> 8], 1);
      pedge[pos] = (uint)s | ((uint)(d & 255) << 24);
    }
  }
}

// ---------------- phase B: exact bucket within each partition ----------------
__global__ __launch_bounds__(256) void k_bucket2(const int* __restrict__ offsets,
                                                 const uint* __restrict__ pedge,
                                                 int* __restrict__ srcs) {
  __shared__ int cur[256];
  int p = blockIdx.x;
  int n0 = p << 8;
  int t = threadIdx.x;
  int hi = n0 + 256; if (hi > NN) hi = NN;
  if (n0 + t < hi) cur[t] = offsets[n0 + t];
  __syncthreads();
  int s = offsets[n0];
  int e = offsets[hi];
  for (int i = s + t; i < e; i += 256) {
    uint v = pedge[i];
    int pos = atomicAdd(&cur[v >> 24], 1);
    srcs[pos] = (int)(v & 0xFFFFFFu);
  }
}

// ---------------- cast x f32 -> bf16 ----------------
__global__ void k_cast(const float4* __restrict__ x, uint2* __restrict__ xb, int n4) {
  int i = blockIdx.x * 256 + threadIdx.x;
  if (i < n4) {
    float4 v = x[i];
    uint2 o;
    o.x = pack2(v.x, v.y);
    o.y = pack2(v.z, v.w);
    xb[i] = o;
  }
}

// ---------------- prep W: f32 [128,128] -> bf16 W^T swizzled ----------------
// wt[c*128 + ((k>>3)^(c&15))*8 + (k&7)] = bf16(W[k][c])
__global__ __launch_bounds__(128) void k_prepW(const float* __restrict__ W,
                                               ushort* __restrict__ wt) {
  int c = blockIdx.x;
  int r = threadIdx.x;
  float v = W[r * 128 + c];
  wt[c * 128 + (((r >> 3) ^ (c & 15)) << 3) + (r & 7)] = f2bf(v);
}

// ---------------- bf16 MFMA GEMM: H[N,128] = X[N,128] @ W ----------------
// 256 threads = 4 waves; each wave: 16 rows x 128 cols. BM=64/block.
__global__ __launch_bounds__(256) void k_gemm(const ushort* __restrict__ Xb,
                                              const ushort* __restrict__ wt,
                                              ushort* __restrict__ Hb) {
  __shared__ ushort sW[128 * 128];
  int t = threadIdx.x;
#pragma unroll
  for (int l = 0; l < 8; ++l) {
    int idx = t + l * 256;
    ((uint4*)sW)[idx] = ((const uint4*)wt)[idx];
  }
  __syncthreads();
  int wid = t >> 6, lane = t & 63;
  int row0 = blockIdx.x * 64 + wid * 16;
  int arow = row0 + (lane & 15);
  if (arow >= NN) arow = NN - 1;  // clamp; stores masked below
  const ushort* aptr = Xb + (size_t)arow * 128 + ((lane >> 4) * 8);
  floatx4 acc[8];
#pragma unroll
  for (int n = 0; n < 8; ++n) acc[n] = (floatx4)(0.f);
#pragma unroll
  for (int kb = 0; kb < 4; ++kb) {
    short8 a = *(const short8*)(aptr + kb * 32);
    int kslot = kb * 4 + (lane >> 4);
#pragma unroll
    for (int n = 0; n < 8; ++n) {
      int col = n * 16 + (lane & 15);
      const ushort* bp = sW + col * 128 + ((kslot ^ (col & 15)) << 3);
      short8 b = *(const short8*)bp;
      acc[n] = __builtin_amdgcn_mfma_f32_16x16x32_bf16(a, b, acc[n], 0, 0, 0);
    }
  }
  int srow_base = row0 + (lane >> 4) * 4;
#pragma unroll
  for (int r = 0; r < 4; ++r) {
    int grow = srow_base + r;
    if (grow < NN) {
      ushort* out = Hb + (size_t)grow * 128 + (lane & 15);
#pragma unroll
      for (int n = 0; n < 8; ++n) out[n * 16] = f2bf(acc[n][r]);
    }
  }
}

// ---------------- pull-mode aggregation on bf16 rows, 8-edge unroll ----------------
// 16-lane group per node (16B = 8 bf16 channels per lane), 16 nodes/block.
__global__ __launch_bounds__(256) void k_agg(const ushort* __restrict__ H,
                                             const float* __restrict__ bias,
                                             const float* __restrict__ dinv,
                                             const int* __restrict__ offsets,
                                             const int* __restrict__ srcs,
                                             ushort* __restrict__ Hout, int do_relu) {
  int node = blockIdx.x * 16 + (threadIdx.x >> 4);
  if (node >= NN) return;
  int c8 = threadIdx.x & 15;  // 16B slot; channels c8*8 .. c8*8+7
  float di = dinv[node];
  int s = offsets[node], e = offsets[node + 1];
  float acc[8];
#pragma unroll
  for (int j = 0; j < 8; ++j) acc[j] = 0.f;
  int i = s;
  for (; i + 7 < e; i += 8) {
    int sx[8];
    float dx[8];
    uint4 vx[8];
#pragma unroll
    for (int u = 0; u < 8; ++u) sx[u] = srcs[i + u];
#pragma unroll
    for (int u = 0; u < 8; ++u) dx[u] = dinv[sx[u]];
#pragma unroll
    for (int u = 0; u < 8; ++u) vx[u] = *((const uint4*)(H + (size_t)sx[u] * 128) + c8);
#pragma unroll
    for (int u = 0; u < 8; ++u) {
      acc[0] += bflo(vx[u].x) * dx[u];
      acc[1] += bfhi(vx[u].x) * dx[u];
      acc[2] += bflo(vx[u].y) * dx[u];
      acc[3] += bfhi(vx[u].y) * dx[u];
      acc[4] += bflo(vx[u].z) * dx[u];
      acc[5] += bfhi(vx[u].z) * dx[u];
      acc[6] += bflo(vx[u].w) * dx[u];
      acc[7] += bfhi(vx[u].w) * dx[u];
    }
  }
  for (; i < e; ++i) {
    int s0 = srcs[i];
    float d0 = dinv[s0];
    uint4 v0 = *((const uint4*)(H + (size_t)s0 * 128) + c8);
    acc[0] += bflo(v0.x) * d0;
    acc[1] += bfhi(v0.x) * d0;
    acc[2] += bflo(v0.y) * d0;
    acc[3] += bfhi(v0.y) * d0;
    acc[4] += bflo(v0.z) * d0;
    acc[5] += bfhi(v0.z) * d0;
    acc[6] += bflo(v0.w) * d0;
    acc[7] += bfhi(v0.w) * d0;
  }
  uint4 hv = *((const uint4*)(H + (size_t)node * 128) + c8);
  float hb[8] = {bflo(hv.x), bfhi(hv.x), bflo(hv.y), bfhi(hv.y),
                 bflo(hv.z), bfhi(hv.z), bflo(hv.w), bfhi(hv.w)};
  float dii = di * di;
  const float* bp = bias + c8 * 8;
  float r[8];
#pragma unroll
  for (int j = 0; j < 8; ++j) {
    float v = acc[j] * di + hb[j] * dii + bp[j];
    if (do_relu) v = fmaxf(v, 0.f);
    r[j] = v;
  }
  uint4 o;
  o.x = pack2(r[0], r[1]);
  o.y = pack2(r[2], r[3]);
  o.z = pack2(r[4], r[5]);
  o.w = pack2(r[6], r[7]);
  *((uint4*)(Hout + (size_t)node * 128) + c8) = o;
}

// ---------------- global mean pool (batch is sorted), bf16 in ----------------
__device__ inline int lower_bound(const int* a, int n, int v) {
  int lo = 0, hi = n;
  while (lo < hi) {
    int m = (lo + hi) >> 1;
    if (a[m] < v) lo = m + 1; else hi = m;
  }
  return lo;
}

__global__ __launch_bounds__(128) void k_pool(const ushort* __restrict__ H,
                                              const int* __restrict__ batch,
                                              float* __restrict__ f) {
  int g = blockIdx.x;
  int c = threadIdx.x;
  int s = lower_bound(batch, NN, g);
  int e = lower_bound(batch, NN, g + 1);
  float acc = 0.f;
#pragma unroll 4
  for (int i = s; i < e; ++i)
    acc += __uint_as_float(((uint)H[(size_t)i * 128 + c]) << 16);
  f[g * 128 + c] = acc / fmaxf((float)(e - s), 1.0f);
}

// ---------------- MLP head: one block per graph ----------------
__global__ __launch_bounds__(512) void k_mlp(const float* __restrict__ f,
    const float* __restrict__ W1, const float* __restrict__ b1,
    const float* __restrict__ W2, const float* __restrict__ b2,
    const float* __restrict__ W3, const float* __restrict__ b3,
    const float* __restrict__ W4, const float* __restrict__ b4,
    float* __restrict__ z) {
  __shared__ float s0[128];
  __shared__ float s1[512];
  __shared__ float s2[256];
  __shared__ float s3[128];
  int g = blockIdx.x;
  int t = threadIdx.x;
  if (t < 128) s0[t] = f[g * 128 + t];
  __syncthreads();
  {
    float a = b1[t];
#pragma unroll 4
    for (int k = 0; k < 128; ++k) a += s0[k] * W1[k * 512 + t];
    s1[t] = fmaxf(a, 0.f);
  }
  __syncthreads();
  if (t < 256) {
    float a = b2[t];
#pragma unroll 4
    for (int k = 0; k < 512; ++k) a += s1[k] * W2[k * 256 + t];
    s2[t] = fmaxf(a, 0.f);
  }
  __syncthreads();
  if (t < 128) {
    float a = b3[t];
#pragma unroll 4
    for (int k = 0; k < 256; ++k) a += s2[k] * W3[k * 128 + t];
    s3[t] = fmaxf(a, 0.f);
  }
  __syncthreads();
  if (t < 64) {
    float a = b4[t];
#pragma unroll 4
    for (int k = 0; k < 128; ++k) a += s3[k] * W4[k * 64 + t];
    z[g * 64 + t] = a;
  }
}

extern "C" void kernel_launch(void* const* d_in, const int* in_sizes, int n_in,
                              void* d_out, int out_size, void* d_ws, size_t ws_size,
                              hipStream_t stream) {
  const float* x    = (const float*)d_in[0];
  const int* ei     = (const int*)d_in[1];
  const int* batch  = (const int*)d_in[2];
  const float* W1   = (const float*)d_in[3];  const float* b1  = (const float*)d_in[4];
  const float* W2   = (const float*)d_in[5];  const float* b2  = (const float*)d_in[6];
  const float* W3   = (const float*)d_in[7];  const float* b3  = (const float*)d_in[8];
  const float* Wf1  = (const float*)d_in[9];  const float* bf1 = (const float*)d_in[10];
  const float* Wf2  = (const float*)d_in[11]; const float* bf2 = (const float*)d_in[12];
  const float* Wf3  = (const float*)d_in[13]; const float* bf3 = (const float*)d_in[14];
  const float* Wf4  = (const float*)d_in[15]; const float* bf4 = (const float*)d_in[16];
  const int* src = ei;
  const int* dst = ei + NE;

  char* ws = (char*)d_ws;
  size_t off = 0;
  auto alloc = [&](size_t bytes) {
    void* p = ws + off;
    off += (bytes + 255) & ~(size_t)255;
    return p;
  };
  ushort* B0     = (ushort*)alloc((size_t)NN * 128 * 2);
  ushort* B1     = (ushort*)alloc((size_t)NN * 128 * 2);
  ushort* B2     = (ushort*)alloc((size_t)NN * 128 * 2);
  float* dinv    = (float*)alloc((size_t)NN * 4);
  int*   cnt     = (int*)alloc((size_t)NN * 4);
  int*   offsets = (int*)alloc((size_t)(NN + 1) * 4);
  int*   srcs    = (int*)alloc((size_t)NE * 4);
  uint*  pedge   = (uint*)alloc((size_t)NE * 4);
  int*   pcur    = (int*)alloc((size_t)PPART * 4);
  int*   bsum    = (int*)alloc((size_t)(NBLK + 1) * 4);
  ushort* wt1    = (ushort*)alloc(128 * 128 * 2);
  ushort* wt2    = (ushort*)alloc(128 * 128 * 2);
  ushort* wt3    = (ushort*)alloc(128 * 128 * 2);

  float* f_out = (float*)d_out;             // [512*128]
  float* z_out = (float*)d_out + NG * HID;  // [512*64]

  hipMemsetAsync(cnt, 0, (size_t)NN * 4, stream);
  k_count<<<(NE + 255) / 256, 256, 0, stream>>>(dst, cnt);
  k_scan1<<<NBLK, 1024, 0, stream>>>(cnt, offsets, bsum);
  k_scan2<<<1, 64, 0, stream>>>(bsum);
  k_scan3<<<NBLK, 1024, 0, stream>>>(cnt, offsets, bsum, dinv);
  k_pinit<<<(PPART + 255) / 256, 256, 0, stream>>>(offsets, pcur);
  k_part<<<(NE + EPB - 1) / EPB, 256, 0, stream>>>(src, dst, pcur, pedge);
  k_bucket2<<<PPART, 256, 0, stream>>>(offsets, pedge, srcs);

  k_prepW<<<128, 128, 0, stream>>>(W1, wt1);
  k_prepW<<<128, 128, 0, stream>>>(W2, wt2);
  k_prepW<<<128, 128, 0, stream>>>(W3, wt3);
  k_cast<<<(NN * 128 / 4 + 255) / 256, 256, 0, stream>>>((const float4*)x, (uint2*)B0, NN * 128 / 4);

  int gemm_grid = (NN + 63) / 64;
  int agg_grid = (NN + 15) / 16;

  // layer 1
  k_gemm<<<gemm_grid, 256, 0, stream>>>(B0, wt1, B1);
  k_agg<<<agg_grid, 256, 0, stream>>>(B1, b1, dinv, offsets, srcs, B2, 1);
  // layer 2
  k_gemm<<<gemm_grid, 256, 0, stream>>>(B2, wt2, B1);
  k_agg<<<agg_grid, 256, 0, stream>>>(B1, b2, dinv, offsets, srcs, B0, 1);
  // layer 3
  k_gemm<<<gemm_grid, 256, 0, stream>>>(B0, wt3, B1);
  k_agg<<<agg_grid, 256, 0, stream>>>(B1, b3, dinv, offsets, srcs, B2, 0);

  k_pool<<<NG, 128, 0, stream>>>(B2, batch, f_out);
  k_mlp<<<NG, 512, 0, stream>>>(f_out, Wf1, bf1, Wf2, bf2, Wf3, bf3, Wf4, bf4, z_out);
}

// Round 8
// 458.319 us; speedup vs baseline: 2.7821x; 1.0357x over previous
//
#include <hip/hip_runtime.h>
#include <hip/hip_bf16.h>

#define NN 100000
#define NE 1600000
#define NG 512
#define HID 128
#define NBLK 98    // ceil(NN/1024)
#define PPART 391  // ceil(NN/256) partitions of 256 nodes
#define EPB 4096   // edges per block in k_part

typedef __attribute__((ext_vector_type(8))) short short8;
typedef __attribute__((ext_vector_type(4))) float floatx4;

__device__ inline ushort f2bf(float f) {
  uint u = __float_as_uint(f);
  u += 0x7fff + ((u >> 16) & 1);
  return (ushort)(u >> 16);
}
__device__ inline uint pack2(float lo, float hi) {
  return (uint)f2bf(lo) | ((uint)f2bf(hi) << 16);
}
__device__ inline float bflo(uint u) { return __uint_as_float(u << 16); }
__device__ inline float bfhi(uint u) { return __uint_as_float(u & 0xffff0000u); }

// ---------------- degree count (in-degree by dst) ----------------
__global__ void k_count(const int* __restrict__ dst, int* __restrict__ cnt) {
  int e = blockIdx.x * 256 + threadIdx.x;
  if (e < NE) atomicAdd(&cnt[dst[e]], 1);
}

// ---------------- multi-block scan ----------------
__global__ __launch_bounds__(1024) void k_scan1(const int* __restrict__ cnt,
                                                int* __restrict__ offs,
                                                int* __restrict__ bsum) {
  __shared__ int wsum[16];
  int t = threadIdx.x, lane = t & 63, wid = t >> 6;
  int i = blockIdx.x * 1024 + t;
  int v = (i < NN) ? cnt[i] : 0;
  int iv = v;
  for (int o = 1; o < 64; o <<= 1) {
    int n = __shfl_up(iv, o, 64);
    if (lane >= o) iv += n;
  }
  if (lane == 63) wsum[wid] = iv;
  __syncthreads();
  if (wid == 0 && lane < 16) {
    int w = wsum[lane];
    for (int o = 1; o < 16; o <<= 1) {
      int n = __shfl_up(w, o, 64);
      if (lane >= o) w += n;
    }
    wsum[lane] = w;
  }
  __syncthreads();
  int excl = iv - v + (wid ? wsum[wid - 1] : 0);
  if (i < NN) offs[i] = excl;
  if (t == 0) bsum[blockIdx.x] = wsum[15];
}

__global__ void k_scan2(int* __restrict__ bsum) {
  if (threadIdx.x == 0) {
    int run = 0;
    for (int b = 0; b < NBLK; ++b) {
      int v = bsum[b];
      bsum[b] = run;
      run += v;
    }
    bsum[NBLK] = run;
  }
}

__global__ __launch_bounds__(1024) void k_scan3(const int* __restrict__ cnt,
                                                int* __restrict__ offs,
                                                const int* __restrict__ bsum,
                                                float* __restrict__ dinv) {
  int i = blockIdx.x * 1024 + threadIdx.x;
  if (i < NN) {
    int o = offs[i] + bsum[blockIdx.x];
    offs[i] = o;
    dinv[i] = 1.0f / sqrtf((float)(cnt[i] + 1));
  }
  if (i == NN - 1) offs[NN] = bsum[NBLK];
}

// ---------------- partition cursor init: pcur[p] = offsets[p*256] ----------------
__global__ void k_pinit(const int* __restrict__ offsets, int* __restrict__ pcur) {
  int p = blockIdx.x * 256 + threadIdx.x;
  if (p < PPART) pcur[p] = offsets[p << 8];
}

// ---------------- phase A: scatter packed edges into partition regions ----------------
__global__ __launch_bounds__(256) void k_part(const int* __restrict__ src,
                                              const int* __restrict__ dst,
                                              int* __restrict__ pcur,
                                              uint* __restrict__ pedge) {
  __shared__ int hist[PPART];
  __shared__ int base[PPART];
  int t = threadIdx.x;
  for (int i = t; i < PPART; i += 256) hist[i] = 0;
  __syncthreads();
  int e0 = blockIdx.x * EPB;
  int d_[16];
#pragma unroll
  for (int l = 0; l < 16; ++l) {
    int e = e0 + l * 256 + t;
    if (e < NE) {
      int d = dst[e];
      d_[l] = d;
      atomicAdd(&hist[d >> 8], 1);
    } else {
      d_[l] = -1;
    }
  }
  __syncthreads();
  for (int i = t; i < PPART; i += 256) {
    int h = hist[i];
    base[i] = h ? atomicAdd(&pcur[i], h) : 0;
  }
  __syncthreads();
#pragma unroll
  for (int l = 0; l < 16; ++l) {
    int e = e0 + l * 256 + t;
    if (e < NE) {
      int d = d_[l];
      int s = src[e];
      int pos = atomicAdd(&base[d >> 8], 1);
      pedge[pos] = (uint)s | ((uint)(d & 255) << 24);
    }
  }
}

// ---------------- phase B: exact bucket within each partition ----------------
__global__ __launch_bounds__(256) void k_bucket2(const int* __restrict__ offsets,
                                                 const uint* __restrict__ pedge,
                                                 int* __restrict__ srcs) {
  __shared__ int cur[256];
  int p = blockIdx.x;
  int n0 = p << 8;
  int t = threadIdx.x;
  int hi = n0 + 256; if (hi > NN) hi = NN;
  if (n0 + t < hi) cur[t] = offsets[n0 + t];
  __syncthreads();
  int s = offsets[n0];
  int e = offsets[hi];
  for (int i = s + t; i < e; i += 256) {
    uint v = pedge[i];
    int pos = atomicAdd(&cur[v >> 24], 1);
    srcs[pos] = (int)(v & 0xFFFFFFu);
  }
}

// ---------------- cast x f32 -> bf16 ----------------
__global__ void k_cast(const float4* __restrict__ x, uint2* __restrict__ xb, int n4) {
  int i = blockIdx.x * 256 + threadIdx.x;
  if (i < n4) {
    float4 v = x[i];
    uint2 o;
    o.x = pack2(v.x, v.y);
    o.y = pack2(v.z, v.w);
    xb[i] = o;
  }
}

// ---------------- prep W: f32 [128,128] -> bf16 W^T swizzled ----------------
// wt[c*128 + ((k>>3)^(c&15))*8 + (k&7)] = bf16(W[k][c])
__global__ __launch_bounds__(128) void k_prepW(const float* __restrict__ W,
                                               ushort* __restrict__ wt) {
  int c = blockIdx.x;
  int r = threadIdx.x;
  float v = W[r * 128 + c];
  wt[c * 128 + (((r >> 3) ^ (c & 15)) << 3) + (r & 7)] = f2bf(v);
}

// ---------------- bf16 MFMA GEMM: H[N,128] = X[N,128] @ W ----------------
// 256 threads = 4 waves; each wave: 16 rows x 128 cols. BM=64/block.
__global__ __launch_bounds__(256) void k_gemm(const ushort* __restrict__ Xb,
                                              const ushort* __restrict__ wt,
                                              ushort* __restrict__ Hb) {
  __shared__ ushort sW[128 * 128];
  int t = threadIdx.x;
#pragma unroll
  for (int l = 0; l < 8; ++l) {
    int idx = t + l * 256;
    ((uint4*)sW)[idx] = ((const uint4*)wt)[idx];
  }
  __syncthreads();
  int wid = t >> 6, lane = t & 63;
  int row0 = blockIdx.x * 64 + wid * 16;
  int arow = row0 + (lane & 15);
  if (arow >= NN) arow = NN - 1;  // clamp; stores masked below
  const ushort* aptr = Xb + (size_t)arow * 128 + ((lane >> 4) * 8);
  floatx4 acc[8];
#pragma unroll
  for (int n = 0; n < 8; ++n) acc[n] = (floatx4)(0.f);
#pragma unroll
  for (int kb = 0; kb < 4; ++kb) {
    short8 a = *(const short8*)(aptr + kb * 32);
    int kslot = kb * 4 + (lane >> 4);
#pragma unroll
    for (int n = 0; n < 8; ++n) {
      int col = n * 16 + (lane & 15);
      const ushort* bp = sW + col * 128 + ((kslot ^ (col & 15)) << 3);
      short8 b = *(const short8*)bp;
      acc[n] = __builtin_amdgcn_mfma_f32_16x16x32_bf16(a, b, acc[n], 0, 0, 0);
    }
  }
  int srow_base = row0 + (lane >> 4) * 4;
#pragma unroll
  for (int r = 0; r < 4; ++r) {
    int grow = srow_base + r;
    if (grow < NN) {
      ushort* out = Hb + (size_t)grow * 128 + (lane & 15);
#pragma unroll
      for (int n = 0; n < 8; ++n) out[n * 16] = f2bf(acc[n][r]);
    }
  }
}

// ---------------- pull-mode aggregation on bf16 rows, 8-edge unroll ----------------
// 16-lane group per node (16B = 8 bf16 channels per lane), 16 nodes/block.
__global__ __launch_bounds__(256) void k_agg(const ushort* __restrict__ H,
                                             const float* __restrict__ bias,
                                             const float* __restrict__ dinv,
                                             const int* __restrict__ offsets,
                                             const int* __restrict__ srcs,
                                             ushort* __restrict__ Hout, int do_relu) {
  int node = blockIdx.x * 16 + (threadIdx.x >> 4);
  if (node >= NN) return;
  int c8 = threadIdx.x & 15;  // 16B slot; channels c8*8 .. c8*8+7
  float di = dinv[node];
  int s = offsets[node], e = offsets[node + 1];
  float acc[8];
#pragma unroll
  for (int j = 0; j < 8; ++j) acc[j] = 0.f;
  int i = s;
  for (; i + 7 < e; i += 8) {
    int sx[8];
    float dx[8];
    uint4 vx[8];
#pragma unroll
    for (int u = 0; u < 8; ++u) sx[u] = srcs[i + u];
#pragma unroll
    for (int u = 0; u < 8; ++u) dx[u] = dinv[sx[u]];
#pragma unroll
    for (int u = 0; u < 8; ++u) vx[u] = *((const uint4*)(H + (size_t)sx[u] * 128) + c8);
#pragma unroll
    for (int u = 0; u < 8; ++u) {
      acc[0] += bflo(vx[u].x) * dx[u];
      acc[1] += bfhi(vx[u].x) * dx[u];
      acc[2] += bflo(vx[u].y) * dx[u];
      acc[3] += bfhi(vx[u].y) * dx[u];
      acc[4] += bflo(vx[u].z) * dx[u];
      acc[5] += bfhi(vx[u].z) * dx[u];
      acc[6] += bflo(vx[u].w) * dx[u];
      acc[7] += bfhi(vx[u].w) * dx[u];
    }
  }
  for (; i < e; ++i) {
    int s0 = srcs[i];
    float d0 = dinv[s0];
    uint4 v0 = *((const uint4*)(H + (size_t)s0 * 128) + c8);
    acc[0] += bflo(v0.x) * d0;
    acc[1] += bfhi(v0.x) * d0;
    acc[2] += bflo(v0.y) * d0;
    acc[3] += bfhi(v0.y) * d0;
    acc[4] += bflo(v0.z) * d0;
    acc[5] += bfhi(v0.z) * d0;
    acc[6] += bflo(v0.w) * d0;
    acc[7] += bfhi(v0.w) * d0;
  }
  uint4 hv = *((const uint4*)(H + (size_t)node * 128) + c8);
  float hb[8] = {bflo(hv.x), bfhi(hv.x), bflo(hv.y), bfhi(hv.y),
                 bflo(hv.z), bfhi(hv.z), bflo(hv.w), bfhi(hv.w)};
  float dii = di * di;
  const float* bp = bias + c8 * 8;
  float r[8];
#pragma unroll
  for (int j = 0; j < 8; ++j) {
    float v = acc[j] * di + hb[j] * dii + bp[j];
    if (do_relu) v = fmaxf(v, 0.f);
    r[j] = v;
  }
  uint4 o;
  o.x = pack2(r[0], r[1]);
  o.y = pack2(r[2], r[3]);
  o.z = pack2(r[4], r[5]);
  o.w = pack2(r[6], r[7]);
  *((uint4*)(Hout + (size_t)node * 128) + c8) = o;
}

// ---------------- global mean pool (batch is sorted), bf16 in ----------------
__device__ inline int lower_bound(const int* a, int n, int v) {
  int lo = 0, hi = n;
  while (lo < hi) {
    int m = (lo + hi) >> 1;
    if (a[m] < v) lo = m + 1; else hi = m;
  }
  return lo;
}

__global__ __launch_bounds__(128) void k_pool(const ushort* __restrict__ H,
                                              const int* __restrict__ batch,
                                              float* __restrict__ f) {
  int g = blockIdx.x;
  int c = threadIdx.x;
  int s = lower_bound(batch, NN, g);
  int e = lower_bound(batch, NN, g + 1);
  float acc = 0.f;
#pragma unroll 4
  for (int i = s; i < e; ++i)
    acc += __uint_as_float(((uint)H[(size_t)i * 128 + c]) << 16);
  f[g * 128 + c] = acc / fmaxf((float)(e - s), 1.0f);
}

// ---------------- MLP as f32 tiled GEMM: Y[M,N] = X[M,K] @ W[K,N] + b ----------------
// 256 threads, 64x64 tile, BK=32, 4x4 register tile per thread.
__global__ __launch_bounds__(256) void k_mgemm(const float* __restrict__ X,
                                               const float* __restrict__ W,
                                               const float* __restrict__ bias,
                                               float* __restrict__ Y,
                                               int M, int K, int N, int do_relu) {
  __shared__ float sA[32][64];  // [k][m]
  __shared__ float sB[32][64];  // [k][n]
  int t = threadIdx.x;
  int tn = t & 15, tm = t >> 4;
  int m0 = blockIdx.y * 64;
  int n0 = blockIdx.x * 64;
  float acc[4][4];
#pragma unroll
  for (int i = 0; i < 4; ++i)
#pragma unroll
    for (int j = 0; j < 4; ++j) acc[i][j] = 0.f;

  for (int kb = 0; kb < K; kb += 32) {
#pragma unroll
    for (int l = 0; l < 2; ++l) {
      int idx = t * 2 + l;          // 0..511
      int r = idx >> 3, kq = idx & 7;
      float4 v = *(const float4*)(X + (size_t)(m0 + r) * K + kb + kq * 4);
      sA[kq * 4 + 0][r] = v.x;
      sA[kq * 4 + 1][r] = v.y;
      sA[kq * 4 + 2][r] = v.z;
      sA[kq * 4 + 3][r] = v.w;
    }
#pragma unroll
    for (int l = 0; l < 2; ++l) {
      int idx = t * 2 + l;
      int kr = idx >> 4, nq = idx & 15;
      *(float4*)&sB[kr][nq * 4] = *(const float4*)(W + (size_t)(kb + kr) * N + n0 + nq * 4);
    }
    __syncthreads();
#pragma unroll
    for (int k = 0; k < 32; ++k) {
      float a[4], b[4];
      *(float4*)a = *(float4*)&sA[k][tm * 4];
      *(float4*)b = *(float4*)&sB[k][tn * 4];
#pragma unroll
      for (int i = 0; i < 4; ++i)
#pragma unroll
        for (int j = 0; j < 4; ++j) acc[i][j] += a[i] * b[j];
    }
    __syncthreads();
  }
  float4 bv = *(const float4*)(bias + n0 + tn * 4);
#pragma unroll
  for (int i = 0; i < 4; ++i) {
    float4 o;
    o.x = acc[i][0] + bv.x;
    o.y = acc[i][1] + bv.y;
    o.z = acc[i][2] + bv.z;
    o.w = acc[i][3] + bv.w;
    if (do_relu) {
      o.x = fmaxf(o.x, 0.f);
      o.y = fmaxf(o.y, 0.f);
      o.z = fmaxf(o.z, 0.f);
      o.w = fmaxf(o.w, 0.f);
    }
    *(float4*)(Y + (size_t)(m0 + tm * 4 + i) * N + n0 + tn * 4) = o;
  }
}

extern "C" void kernel_launch(void* const* d_in, const int* in_sizes, int n_in,
                              void* d_out, int out_size, void* d_ws, size_t ws_size,
                              hipStream_t stream) {
  const float* x    = (const float*)d_in[0];
  const int* ei     = (const int*)d_in[1];
  const int* batch  = (const int*)d_in[2];
  const float* W1   = (const float*)d_in[3];  const float* b1  = (const float*)d_in[4];
  const float* W2   = (const float*)d_in[5];  const float* b2  = (const float*)d_in[6];
  const float* W3   = (const float*)d_in[7];  const float* b3  = (const float*)d_in[8];
  const float* Wf1  = (const float*)d_in[9];  const float* bf1 = (const float*)d_in[10];
  const float* Wf2  = (const float*)d_in[11]; const float* bf2 = (const float*)d_in[12];
  const float* Wf3  = (const float*)d_in[13]; const float* bf3 = (const float*)d_in[14];
  const float* Wf4  = (const float*)d_in[15]; const float* bf4 = (const float*)d_in[16];
  const int* src = ei;
  const int* dst = ei + NE;

  char* ws = (char*)d_ws;
  size_t off = 0;
  auto alloc = [&](size_t bytes) {
    void* p = ws + off;
    off += (bytes + 255) & ~(size_t)255;
    return p;
  };
  ushort* B0     = (ushort*)alloc((size_t)NN * 128 * 2);
  ushort* B1     = (ushort*)alloc((size_t)NN * 128 * 2);
  ushort* B2     = (ushort*)alloc((size_t)NN * 128 * 2);
  float* dinv    = (float*)alloc((size_t)NN * 4);
  int*   cnt     = (int*)alloc((size_t)NN * 4);
  int*   offsets = (int*)alloc((size_t)(NN + 1) * 4);
  int*   srcs    = (int*)alloc((size_t)NE * 4);
  uint*  pedge   = (uint*)alloc((size_t)NE * 4);
  int*   pcur    = (int*)alloc((size_t)PPART * 4);
  int*   bsum    = (int*)alloc((size_t)(NBLK + 1) * 4);
  ushort* wt1    = (ushort*)alloc(128 * 128 * 2);
  ushort* wt2    = (ushort*)alloc(128 * 128 * 2);
  ushort* wt3    = (ushort*)alloc(128 * 128 * 2);
  float* t1      = (float*)alloc((size_t)NG * 512 * 4);
  float* t2      = (float*)alloc((size_t)NG * 256 * 4);
  float* t3      = (float*)alloc((size_t)NG * 128 * 4);

  float* f_out = (float*)d_out;             // [512*128]
  float* z_out = (float*)d_out + NG * HID;  // [512*64]

  hipMemsetAsync(cnt, 0, (size_t)NN * 4, stream);
  k_count<<<(NE + 255) / 256, 256, 0, stream>>>(dst, cnt);
  k_scan1<<<NBLK, 1024, 0, stream>>>(cnt, offsets, bsum);
  k_scan2<<<1, 64, 0, stream>>>(bsum);
  k_scan3<<<NBLK, 1024, 0, stream>>>(cnt, offsets, bsum, dinv);
  k_pinit<<<(PPART + 255) / 256, 256, 0, stream>>>(offsets, pcur);
  k_part<<<(NE + EPB - 1) / EPB, 256, 0, stream>>>(src, dst, pcur, pedge);
  k_bucket2<<<PPART, 256, 0, stream>>>(offsets, pedge, srcs);

  k_prepW<<<128, 128, 0, stream>>>(W1, wt1);
  k_prepW<<<128, 128, 0, stream>>>(W2, wt2);
  k_prepW<<<128, 128, 0, stream>>>(W3, wt3);
  k_cast<<<(NN * 128 / 4 + 255) / 256, 256, 0, stream>>>((const float4*)x, (uint2*)B0, NN * 128 / 4);

  int gemm_grid = (NN + 63) / 64;
  int agg_grid = (NN + 15) / 16;

  // layer 1
  k_gemm<<<gemm_grid, 256, 0, stream>>>(B0, wt1, B1);
  k_agg<<<agg_grid, 256, 0, stream>>>(B1, b1, dinv, offsets, srcs, B2, 1);
  // layer 2
  k_gemm<<<gemm_grid, 256, 0, stream>>>(B2, wt2, B1);
  k_agg<<<agg_grid, 256, 0, stream>>>(B1, b2, dinv, offsets, srcs, B0, 1);
  // layer 3
  k_gemm<<<gemm_grid, 256, 0, stream>>>(B0, wt3, B1);
  k_agg<<<agg_grid, 256, 0, stream>>>(B1, b3, dinv, offsets, srcs, B2, 0);

  k_pool<<<NG, 128, 0, stream>>>(B2, batch, f_out);

  // MLP head as 4 tiled f32 GEMMs over the whole batch (M=512)
  k_mgemm<<<dim3(8, 8), 256, 0, stream>>>(f_out, Wf1, bf1, t1, NG, 128, 512, 1);
  k_mgemm<<<dim3(4, 8), 256, 0, stream>>>(t1, Wf2, bf2, t2, NG, 512, 256, 1);
  k_mgemm<<<dim3(2, 8), 256, 0, stream>>>(t2, Wf3, bf3, t3, NG, 256, 128, 1);
  k_mgemm<<<dim3(1, 8), 256, 0, stream>>>(t3, Wf4, bf4, z_out, NG, 128, 64, 0);
}

// Round 9
// 387.484 us; speedup vs baseline: 3.2907x; 1.1828x over previous
//
#include <hip/hip_runtime.h>
#include <hip/hip_bf16.h>

#define NN 100000
#define NE 1600000
#define NG 512
#define HID 128
#define PPART 391  // ceil(NN/256) partitions of 256 nodes
#define EPB 4096   // edges per block in k_hist/k_part

typedef __attribute__((ext_vector_type(8))) short short8;
typedef __attribute__((ext_vector_type(4))) float floatx4;

__device__ inline ushort f2bf(float f) {
  uint u = __float_as_uint(f);
  u += 0x7fff + ((u >> 16) & 1);
  return (ushort)(u >> 16);
}
__device__ inline uint pack2(float lo, float hi) {
  return (uint)f2bf(lo) | ((uint)f2bf(hi) << 16);
}
__device__ inline float bflo(uint u) { return __uint_as_float(u << 16); }
__device__ inline float bfhi(uint u) { return __uint_as_float(u & 0xffff0000u); }

// ---------------- per-partition histogram (LDS-absorbed atomics) ----------------
__global__ __launch_bounds__(256) void k_hist(const int* __restrict__ dst,
                                              int* __restrict__ phist) {
  __shared__ int h[PPART];
  int t = threadIdx.x;
  for (int i = t; i < PPART; i += 256) h[i] = 0;
  __syncthreads();
  int e0 = blockIdx.x * EPB;
#pragma unroll
  for (int l = 0; l < 16; ++l) {
    int e = e0 + l * 256 + t;
    if (e < NE) atomicAdd(&h[dst[e] >> 8], 1);
  }
  __syncthreads();
  for (int i = t; i < PPART; i += 256)
    if (h[i]) atomicAdd(&phist[i], h[i]);
}

// ---------------- scan partition sizes -> pbase[0..PPART] ----------------
__global__ __launch_bounds__(512) void k_pscan(const int* __restrict__ phist,
                                               int* __restrict__ pbase) {
  __shared__ int ws[8];
  int t = threadIdx.x, lane = t & 63, wid = t >> 6;
  int v = (t < PPART) ? phist[t] : 0;
  int iv = v;
  for (int o = 1; o < 64; o <<= 1) {
    int n = __shfl_up(iv, o, 64);
    if (lane >= o) iv += n;
  }
  if (lane == 63) ws[wid] = iv;
  __syncthreads();
  int add = 0;
#pragma unroll
  for (int w = 0; w < 8; ++w) add += (w < wid) ? ws[w] : 0;
  if (t < PPART) pbase[t] = iv - v + add;
  if (t == 0) {
    int tot = 0;
#pragma unroll
    for (int w = 0; w < 8; ++w) tot += ws[w];
    pbase[PPART] = tot;
  }
}

__global__ void k_pinit(const int* __restrict__ pbase, int* __restrict__ pcur) {
  int p = blockIdx.x * 256 + threadIdx.x;
  if (p < PPART) pcur[p] = pbase[p];
}

// ---------------- phase A: scatter packed edges into partition windows ----------------
__global__ __launch_bounds__(256) void k_part(const int* __restrict__ src,
                                              const int* __restrict__ dst,
                                              int* __restrict__ pcur,
                                              uint* __restrict__ pedge) {
  __shared__ int hist[PPART];
  __shared__ int base[PPART];
  int t = threadIdx.x;
  for (int i = t; i < PPART; i += 256) hist[i] = 0;
  __syncthreads();
  int e0 = blockIdx.x * EPB;
  int d_[16];
#pragma unroll
  for (int l = 0; l < 16; ++l) {
    int e = e0 + l * 256 + t;
    if (e < NE) {
      int d = dst[e];
      d_[l] = d;
      atomicAdd(&hist[d >> 8], 1);
    } else {
      d_[l] = -1;
    }
  }
  __syncthreads();
  for (int i = t; i < PPART; i += 256) {
    int h = hist[i];
    base[i] = h ? atomicAdd(&pcur[i], h) : 0;
  }
  __syncthreads();
#pragma unroll
  for (int l = 0; l < 16; ++l) {
    int e = e0 + l * 256 + t;
    if (e < NE) {
      int d = d_[l];
      int s = src[e];
      int pos = atomicAdd(&base[d >> 8], 1);
      pedge[pos] = (uint)s | ((uint)(d & 255) << 24);
    }
  }
}

// ---------------- phase B: per-partition count+scan+bucket; emits offsets & dinv ----------------
__global__ __launch_bounds__(256) void k_bucket2(const int* __restrict__ pbase,
                                                 const uint* __restrict__ pedge,
                                                 int* __restrict__ srcs,
                                                 int* __restrict__ offsets,
                                                 float* __restrict__ dinv) {
  __shared__ int cnt_s[256];
  __shared__ int cur[256];
  __shared__ int ws[4];
  int p = blockIdx.x;
  int n0 = p << 8;
  int t = threadIdx.x;
  int lim = NN - n0; if (lim > 256) lim = 256;
  int s = pbase[p], e = pbase[p + 1];
  cnt_s[t] = 0;
  __syncthreads();
  for (int i = s + t; i < e; i += 256) atomicAdd(&cnt_s[pedge[i] >> 24], 1);
  __syncthreads();
  int v = cnt_s[t];
  // block exclusive scan over 256
  int lane = t & 63, wid = t >> 6;
  int iv = v;
  for (int o = 1; o < 64; o <<= 1) {
    int n = __shfl_up(iv, o, 64);
    if (lane >= o) iv += n;
  }
  if (lane == 63) ws[wid] = iv;
  __syncthreads();
  int add = 0;
#pragma unroll
  for (int w = 0; w < 4; ++w) add += (w < wid) ? ws[w] : 0;
  int excl = iv - v + add;
  if (t < lim) {
    int o = s + excl;
    offsets[n0 + t] = o;
    cur[t] = o;
    dinv[n0 + t] = 1.0f / sqrtf((float)(v + 1));
  }
  if (p == PPART - 1 && t == 0) offsets[NN] = NE;
  __syncthreads();
  for (int i = s + t; i < e; i += 256) {
    uint pv = pedge[i];
    int pos = atomicAdd(&cur[pv >> 24], 1);
    srcs[pos] = (int)(pv & 0xFFFFFFu);
  }
}

// ---------------- cast x f32 -> bf16 ----------------
__global__ void k_cast(const float4* __restrict__ x, uint2* __restrict__ xb, int n4) {
  int i = blockIdx.x * 256 + threadIdx.x;
  if (i < n4) {
    float4 v = x[i];
    uint2 o;
    o.x = pack2(v.x, v.y);
    o.y = pack2(v.z, v.w);
    xb[i] = o;
  }
}

// ---------------- prep W: f32 [128,128] -> bf16 W^T swizzled ----------------
__global__ __launch_bounds__(128) void k_prepW(const float* __restrict__ W,
                                               ushort* __restrict__ wt) {
  int c = blockIdx.x;
  int r = threadIdx.x;
  float v = W[r * 128 + c];
  wt[c * 128 + (((r >> 3) ^ (c & 15)) << 3) + (r & 7)] = f2bf(v);
}

// ---------------- bf16 MFMA GEMM: H[N,128] = X[N,128] @ W ----------------
__global__ __launch_bounds__(256) void k_gemm(const ushort* __restrict__ Xb,
                                              const ushort* __restrict__ wt,
                                              ushort* __restrict__ Hb) {
  __shared__ ushort sW[128 * 128];
  int t = threadIdx.x;
#pragma unroll
  for (int l = 0; l < 8; ++l) {
    int idx = t + l * 256;
    ((uint4*)sW)[idx] = ((const uint4*)wt)[idx];
  }
  __syncthreads();
  int wid = t >> 6, lane = t & 63;
  int row0 = blockIdx.x * 64 + wid * 16;
  int arow = row0 + (lane & 15);
  if (arow >= NN) arow = NN - 1;  // clamp; stores masked below
  const ushort* aptr = Xb + (size_t)arow * 128 + ((lane >> 4) * 8);
  floatx4 acc[8];
#pragma unroll
  for (int n = 0; n < 8; ++n) acc[n] = (floatx4)(0.f);
#pragma unroll
  for (int kb = 0; kb < 4; ++kb) {
    short8 a = *(const short8*)(aptr + kb * 32);
    int kslot = kb * 4 + (lane >> 4);
#pragma unroll
    for (int n = 0; n < 8; ++n) {
      int col = n * 16 + (lane & 15);
      const ushort* bp = sW + col * 128 + ((kslot ^ (col & 15)) << 3);
      short8 b = *(const short8*)bp;
      acc[n] = __builtin_amdgcn_mfma_f32_16x16x32_bf16(a, b, acc[n], 0, 0, 0);
    }
  }
  int srow_base = row0 + (lane >> 4) * 4;
#pragma unroll
  for (int r = 0; r < 4; ++r) {
    int grow = srow_base + r;
    if (grow < NN) {
      ushort* out = Hb + (size_t)grow * 128 + (lane & 15);
#pragma unroll
      for (int n = 0; n < 8; ++n) out[n * 16] = f2bf(acc[n][r]);
    }
  }
}

// ---------------- pull-mode aggregation on bf16 rows, 8-edge unroll ----------------
__global__ __launch_bounds__(256) void k_agg(const ushort* __restrict__ H,
                                             const float* __restrict__ bias,
                                             const float* __restrict__ dinv,
                                             const int* __restrict__ offsets,
                                             const int* __restrict__ srcs,
                                             ushort* __restrict__ Hout, int do_relu) {
  int node = blockIdx.x * 16 + (threadIdx.x >> 4);
  if (node >= NN) return;
  int c8 = threadIdx.x & 15;  // 16B slot; channels c8*8 .. c8*8+7
  float di = dinv[node];
  int s = offsets[node], e = offsets[node + 1];
  float acc[8];
#pragma unroll
  for (int j = 0; j < 8; ++j) acc[j] = 0.f;
  int i = s;
  for (; i + 7 < e; i += 8) {
    int sx[8];
    float dx[8];
    uint4 vx[8];
#pragma unroll
    for (int u = 0; u < 8; ++u) sx[u] = srcs[i + u];
#pragma unroll
    for (int u = 0; u < 8; ++u) dx[u] = dinv[sx[u]];
#pragma unroll
    for (int u = 0; u < 8; ++u) vx[u] = *((const uint4*)(H + (size_t)sx[u] * 128) + c8);
#pragma unroll
    for (int u = 0; u < 8; ++u) {
      acc[0] += bflo(vx[u].x) * dx[u];
      acc[1] += bfhi(vx[u].x) * dx[u];
      acc[2] += bflo(vx[u].y) * dx[u];
      acc[3] += bfhi(vx[u].y) * dx[u];
      acc[4] += bflo(vx[u].z) * dx[u];
      acc[5] += bfhi(vx[u].z) * dx[u];
      acc[6] += bflo(vx[u].w) * dx[u];
      acc[7] += bfhi(vx[u].w) * dx[u];
    }
  }
  for (; i < e; ++i) {
    int s0 = srcs[i];
    float d0 = dinv[s0];
    uint4 v0 = *((const uint4*)(H + (size_t)s0 * 128) + c8);
    acc[0] += bflo(v0.x) * d0;
    acc[1] += bfhi(v0.x) * d0;
    acc[2] += bflo(v0.y) * d0;
    acc[3] += bfhi(v0.y) * d0;
    acc[4] += bflo(v0.z) * d0;
    acc[5] += bfhi(v0.z) * d0;
    acc[6] += bflo(v0.w) * d0;
    acc[7] += bfhi(v0.w) * d0;
  }
  uint4 hv = *((const uint4*)(H + (size_t)node * 128) + c8);
  float hb[8] = {bflo(hv.x), bfhi(hv.x), bflo(hv.y), bfhi(hv.y),
                 bflo(hv.z), bfhi(hv.z), bflo(hv.w), bfhi(hv.w)};
  float dii = di * di;
  const float* bp = bias + c8 * 8;
  float r[8];
#pragma unroll
  for (int j = 0; j < 8; ++j) {
    float vv = acc[j] * di + hb[j] * dii + bp[j];
    if (do_relu) vv = fmaxf(vv, 0.f);
    r[j] = vv;
  }
  uint4 o;
  o.x = pack2(r[0], r[1]);
  o.y = pack2(r[2], r[3]);
  o.z = pack2(r[4], r[5]);
  o.w = pack2(r[6], r[7]);
  *((uint4*)(Hout + (size_t)node * 128) + c8) = o;
}

// ---------------- global mean pool (batch is sorted), bf16 in ----------------
__device__ inline int lower_bound(const int* a, int n, int v) {
  int lo = 0, hi = n;
  while (lo < hi) {
    int m = (lo + hi) >> 1;
    if (a[m] < v) lo = m + 1; else hi = m;
  }
  return lo;
}

__global__ __launch_bounds__(128) void k_pool(const ushort* __restrict__ H,
                                              const int* __restrict__ batch,
                                              float* __restrict__ f) {
  int g = blockIdx.x;
  int c = threadIdx.x;
  int s = lower_bound(batch, NN, g);
  int e = lower_bound(batch, NN, g + 1);
  float acc = 0.f;
#pragma unroll 4
  for (int i = s; i < e; ++i)
    acc += __uint_as_float(((uint)H[(size_t)i * 128 + c]) << 16);
  f[g * 128 + c] = acc / fmaxf((float)(e - s), 1.0f);
}

// ---------------- MLP as f32 tiled GEMM: Y[M,N] = X[M,K] @ W[K,N] + b ----------------
// 256 threads, 32x64 tile (M x N), BK=32, 2x4 register tile per thread.
__global__ __launch_bounds__(256) void k_mgemm(const float* __restrict__ X,
                                               const float* __restrict__ W,
                                               const float* __restrict__ bias,
                                               float* __restrict__ Y,
                                               int M, int K, int N, int do_relu) {
  __shared__ float sA[32][32];  // [k][m]
  __shared__ float sB[32][64];  // [k][n]
  int t = threadIdx.x;
  int tn = t & 15, tm = t >> 4;
  int m0 = blockIdx.y * 32;
  int n0 = blockIdx.x * 64;
  float acc[2][4];
#pragma unroll
  for (int i = 0; i < 2; ++i)
#pragma unroll
    for (int j = 0; j < 4; ++j) acc[i][j] = 0.f;

  for (int kb = 0; kb < K; kb += 32) {
    {
      int r = t >> 3, kq = t & 7;  // 32 rows x 8 float4
      float4 v = *(const float4*)(X + (size_t)(m0 + r) * K + kb + kq * 4);
      sA[kq * 4 + 0][r] = v.x;
      sA[kq * 4 + 1][r] = v.y;
      sA[kq * 4 + 2][r] = v.z;
      sA[kq * 4 + 3][r] = v.w;
    }
#pragma unroll
    for (int l = 0; l < 2; ++l) {
      int idx = t * 2 + l;
      int kr = idx >> 4, nq = idx & 15;
      *(float4*)&sB[kr][nq * 4] = *(const float4*)(W + (size_t)(kb + kr) * N + n0 + nq * 4);
    }
    __syncthreads();
#pragma unroll
    for (int k = 0; k < 32; ++k) {
      float a[2], b[4];
      a[0] = sA[k][tm * 2];
      a[1] = sA[k][tm * 2 + 1];
      *(float4*)b = *(float4*)&sB[k][tn * 4];
#pragma unroll
      for (int i = 0; i < 2; ++i)
#pragma unroll
        for (int j = 0; j < 4; ++j) acc[i][j] += a[i] * b[j];
    }
    __syncthreads();
  }
  float4 bv = *(const float4*)(bias + n0 + tn * 4);
#pragma unroll
  for (int i = 0; i < 2; ++i) {
    float4 o;
    o.x = acc[i][0] + bv.x;
    o.y = acc[i][1] + bv.y;
    o.z = acc[i][2] + bv.z;
    o.w = acc[i][3] + bv.w;
    if (do_relu) {
      o.x = fmaxf(o.x, 0.f);
      o.y = fmaxf(o.y, 0.f);
      o.z = fmaxf(o.z, 0.f);
      o.w = fmaxf(o.w, 0.f);
    }
    *(float4*)(Y + (size_t)(m0 + tm * 2 + i) * N + n0 + tn * 4) = o;
  }
}

extern "C" void kernel_launch(void* const* d_in, const int* in_sizes, int n_in,
                              void* d_out, int out_size, void* d_ws, size_t ws_size,
                              hipStream_t stream) {
  const float* x    = (const float*)d_in[0];
  const int* ei     = (const int*)d_in[1];
  const int* batch  = (const int*)d_in[2];
  const float* W1   = (const float*)d_in[3];  const float* b1  = (const float*)d_in[4];
  const float* W2   = (const float*)d_in[5];  const float* b2  = (const float*)d_in[6];
  const float* W3   = (const float*)d_in[7];  const float* b3  = (const float*)d_in[8];
  const float* Wf1  = (const float*)d_in[9];  const float* bf1 = (const float*)d_in[10];
  const float* Wf2  = (const float*)d_in[11]; const float* bf2 = (const float*)d_in[12];
  const float* Wf3  = (const float*)d_in[13]; const float* bf3 = (const float*)d_in[14];
  const float* Wf4  = (const float*)d_in[15]; const float* bf4 = (const float*)d_in[16];
  const int* src = ei;
  const int* dst = ei + NE;

  char* ws = (char*)d_ws;
  size_t off = 0;
  auto alloc = [&](size_t bytes) {
    void* p = ws + off;
    off += (bytes + 255) & ~(size_t)255;
    return p;
  };
  ushort* B0     = (ushort*)alloc((size_t)NN * 128 * 2);
  ushort* B1     = (ushort*)alloc((size_t)NN * 128 * 2);
  ushort* B2     = (ushort*)alloc((size_t)NN * 128 * 2);
  float* dinv    = (float*)alloc((size_t)NN * 4);
  int*   offsets = (int*)alloc((size_t)(NN + 1) * 4);
  int*   srcs    = (int*)alloc((size_t)NE * 4);
  uint*  pedge   = (uint*)alloc((size_t)NE * 4);
  int*   phist   = (int*)alloc((size_t)PPART * 4);
  int*   pbase   = (int*)alloc((size_t)(PPART + 1) * 4);
  int*   pcur    = (int*)alloc((size_t)PPART * 4);
  ushort* wt1    = (ushort*)alloc(128 * 128 * 2);
  ushort* wt2    = (ushort*)alloc(128 * 128 * 2);
  ushort* wt3    = (ushort*)alloc(128 * 128 * 2);
  float* t1      = (float*)alloc((size_t)NG * 512 * 4);
  float* t2      = (float*)alloc((size_t)NG * 256 * 4);
  float* t3      = (float*)alloc((size_t)NG * 128 * 4);

  float* f_out = (float*)d_out;             // [512*128]
  float* z_out = (float*)d_out + NG * HID;  // [512*64]

  // ---- preprocessing: partition-count -> scan -> scatter -> in-partition bucket ----
  hipMemsetAsync(phist, 0, (size_t)PPART * 4, stream);
  k_hist<<<(NE + EPB - 1) / EPB, 256, 0, stream>>>(dst, phist);
  k_pscan<<<1, 512, 0, stream>>>(phist, pbase);
  k_pinit<<<(PPART + 255) / 256, 256, 0, stream>>>(pbase, pcur);
  k_part<<<(NE + EPB - 1) / EPB, 256, 0, stream>>>(src, dst, pcur, pedge);
  k_bucket2<<<PPART, 256, 0, stream>>>(pbase, pedge, srcs, offsets, dinv);

  k_prepW<<<128, 128, 0, stream>>>(W1, wt1);
  k_prepW<<<128, 128, 0, stream>>>(W2, wt2);
  k_prepW<<<128, 128, 0, stream>>>(W3, wt3);
  k_cast<<<(NN * 128 / 4 + 255) / 256, 256, 0, stream>>>((const float4*)x, (uint2*)B0, NN * 128 / 4);

  int gemm_grid = (NN + 63) / 64;
  int agg_grid = (NN + 15) / 16;

  // layer 1
  k_gemm<<<gemm_grid, 256, 0, stream>>>(B0, wt1, B1);
  k_agg<<<agg_grid, 256, 0, stream>>>(B1, b1, dinv, offsets, srcs, B2, 1);
  // layer 2
  k_gemm<<<gemm_grid, 256, 0, stream>>>(B2, wt2, B1);
  k_agg<<<agg_grid, 256, 0, stream>>>(B1, b2, dinv, offsets, srcs, B0, 1);
  // layer 3
  k_gemm<<<gemm_grid, 256, 0, stream>>>(B0, wt3, B1);
  k_agg<<<agg_grid, 256, 0, stream>>>(B1, b3, dinv, offsets, srcs, B2, 0);

  k_pool<<<NG, 128, 0, stream>>>(B2, batch, f_out);

  // MLP head as 4 tiled f32 GEMMs over the whole batch (M=512)
  k_mgemm<<<dim3(8, 16), 256, 0, stream>>>(f_out, Wf1, bf1, t1, NG, 128, 512, 1);
  k_mgemm<<<dim3(4, 16), 256, 0, stream>>>(t1, Wf2, bf2, t2, NG, 512, 256, 1);
  k_mgemm<<<dim3(2, 16), 256, 0, stream>>>(t2, Wf3, bf3, t3, NG, 256, 128, 1);
  k_mgemm<<<dim3(1, 16), 256, 0, stream>>>(t3, Wf4, bf4, z_out, NG, 128, 64, 0);
}

// Round 10
// 381.440 us; speedup vs baseline: 3.3428x; 1.0158x over previous
//
#include <hip/hip_runtime.h>
#include <hip/hip_bf16.h>

#define NN 100000
#define NE 1600000
#define NG 512
#define HID 128
#define PPART 391  // ceil(NN/256) partitions of 256 nodes
#define EPB 4096   // edges per block in k_hist/k_part

typedef __attribute__((ext_vector_type(8))) short short8;
typedef __attribute__((ext_vector_type(4))) float floatx4;

__device__ inline ushort f2bf(float f) {
  uint u = __float_as_uint(f);
  u += 0x7fff + ((u >> 16) & 1);
  return (ushort)(u >> 16);
}
__device__ inline uint pack2(float lo, float hi) {
  return (uint)f2bf(lo) | ((uint)f2bf(hi) << 16);
}
__device__ inline float bflo(uint u) { return __uint_as_float(u << 16); }
__device__ inline float bfhi(uint u) { return __uint_as_float(u & 0xffff0000u); }

// ---------------- per-partition histogram (LDS-absorbed atomics) ----------------
__global__ __launch_bounds__(256) void k_hist(const int* __restrict__ dst,
                                              int* __restrict__ phist) {
  __shared__ int h[PPART];
  int t = threadIdx.x;
  for (int i = t; i < PPART; i += 256) h[i] = 0;
  __syncthreads();
  int e0 = blockIdx.x * EPB;
#pragma unroll
  for (int l = 0; l < 16; ++l) {
    int e = e0 + l * 256 + t;
    if (e < NE) atomicAdd(&h[dst[e] >> 8], 1);
  }
  __syncthreads();
  for (int i = t; i < PPART; i += 256)
    if (h[i]) atomicAdd(&phist[i], h[i]);
}

// ---------------- scan partition sizes -> pbase[0..PPART] ----------------
__global__ __launch_bounds__(512) void k_pscan(const int* __restrict__ phist,
                                               int* __restrict__ pbase) {
  __shared__ int ws[8];
  int t = threadIdx.x, lane = t & 63, wid = t >> 6;
  int v = (t < PPART) ? phist[t] : 0;
  int iv = v;
  for (int o = 1; o < 64; o <<= 1) {
    int n = __shfl_up(iv, o, 64);
    if (lane >= o) iv += n;
  }
  if (lane == 63) ws[wid] = iv;
  __syncthreads();
  int add = 0;
#pragma unroll
  for (int w = 0; w < 8; ++w) add += (w < wid) ? ws[w] : 0;
  if (t < PPART) pbase[t] = iv - v + add;
  if (t == 0) {
    int tot = 0;
#pragma unroll
    for (int w = 0; w < 8; ++w) tot += ws[w];
    pbase[PPART] = tot;
  }
}

__global__ void k_pinit(const int* __restrict__ pbase, int* __restrict__ pcur) {
  int p = blockIdx.x * 256 + threadIdx.x;
  if (p < PPART) pcur[p] = pbase[p];
}

// ---------------- phase A: scatter packed edges into partition windows ----------------
__global__ __launch_bounds__(256) void k_part(const int* __restrict__ src,
                                              const int* __restrict__ dst,
                                              int* __restrict__ pcur,
                                              uint* __restrict__ pedge) {
  __shared__ int hist[PPART];
  __shared__ int base[PPART];
  int t = threadIdx.x;
  for (int i = t; i < PPART; i += 256) hist[i] = 0;
  __syncthreads();
  int e0 = blockIdx.x * EPB;
  int d_[16];
#pragma unroll
  for (int l = 0; l < 16; ++l) {
    int e = e0 + l * 256 + t;
    if (e < NE) {
      int d = dst[e];
      d_[l] = d;
      atomicAdd(&hist[d >> 8], 1);
    } else {
      d_[l] = -1;
    }
  }
  __syncthreads();
  for (int i = t; i < PPART; i += 256) {
    int h = hist[i];
    base[i] = h ? atomicAdd(&pcur[i], h) : 0;
  }
  __syncthreads();
#pragma unroll
  for (int l = 0; l < 16; ++l) {
    int e = e0 + l * 256 + t;
    if (e < NE) {
      int d = d_[l];
      int s = src[e];
      int pos = atomicAdd(&base[d >> 8], 1);
      pedge[pos] = (uint)s | ((uint)(d & 255) << 24);
    }
  }
}

// ---------------- phase B: per-partition count+scan+bucket; emits offsets & dinv ----------------
__global__ __launch_bounds__(256) void k_bucket2(const int* __restrict__ pbase,
                                                 const uint* __restrict__ pedge,
                                                 int* __restrict__ srcs,
                                                 int* __restrict__ offsets,
                                                 float* __restrict__ dinv) {
  __shared__ int cnt_s[256];
  __shared__ int cur[256];
  __shared__ int ws[4];
  int p = blockIdx.x;
  int n0 = p << 8;
  int t = threadIdx.x;
  int lim = NN - n0; if (lim > 256) lim = 256;
  int s = pbase[p], e = pbase[p + 1];
  cnt_s[t] = 0;
  __syncthreads();
  for (int i = s + t; i < e; i += 256) atomicAdd(&cnt_s[pedge[i] >> 24], 1);
  __syncthreads();
  int v = cnt_s[t];
  // block exclusive scan over 256
  int lane = t & 63, wid = t >> 6;
  int iv = v;
  for (int o = 1; o < 64; o <<= 1) {
    int n = __shfl_up(iv, o, 64);
    if (lane >= o) iv += n;
  }
  if (lane == 63) ws[wid] = iv;
  __syncthreads();
  int add = 0;
#pragma unroll
  for (int w = 0; w < 4; ++w) add += (w < wid) ? ws[w] : 0;
  int excl = iv - v + add;
  if (t < lim) {
    int o = s + excl;
    offsets[n0 + t] = o;
    cur[t] = o;
    dinv[n0 + t] = 1.0f / sqrtf((float)(v + 1));
  }
  if (p == PPART - 1 && t == 0) offsets[NN] = NE;
  __syncthreads();
  for (int i = s + t; i < e; i += 256) {
    uint pv = pedge[i];
    int pos = atomicAdd(&cur[pv >> 24], 1);
    srcs[pos] = (int)(pv & 0xFFFFFFu);
  }
}

// ---------------- cast x f32 -> bf16 ----------------
__global__ void k_cast(const float4* __restrict__ x, uint2* __restrict__ xb, int n4) {
  int i = blockIdx.x * 256 + threadIdx.x;
  if (i < n4) {
    float4 v = x[i];
    uint2 o;
    o.x = pack2(v.x, v.y);
    o.y = pack2(v.z, v.w);
    xb[i] = o;
  }
}

// ---------------- prep W: f32 [128,128] -> bf16 W^T swizzled ----------------
__global__ __launch_bounds__(128) void k_prepW(const float* __restrict__ W,
                                               ushort* __restrict__ wt) {
  int c = blockIdx.x;
  int r = threadIdx.x;
  float v = W[r * 128 + c];
  wt[c * 128 + (((r >> 3) ^ (c & 15)) << 3) + (r & 7)] = f2bf(v);
}

// ---------------- bf16 MFMA GEMM: H[N,128] = X[N,128] @ W ----------------
__global__ __launch_bounds__(256) void k_gemm(const ushort* __restrict__ Xb,
                                              const ushort* __restrict__ wt,
                                              ushort* __restrict__ Hb) {
  __shared__ ushort sW[128 * 128];
  int t = threadIdx.x;
#pragma unroll
  for (int l = 0; l < 8; ++l) {
    int idx = t + l * 256;
    ((uint4*)sW)[idx] = ((const uint4*)wt)[idx];
  }
  __syncthreads();
  int wid = t >> 6, lane = t & 63;
  int row0 = blockIdx.x * 64 + wid * 16;
  int arow = row0 + (lane & 15);
  if (arow >= NN) arow = NN - 1;  // clamp; stores masked below
  const ushort* aptr = Xb + (size_t)arow * 128 + ((lane >> 4) * 8);
  floatx4 acc[8];
#pragma unroll
  for (int n = 0; n < 8; ++n) acc[n] = (floatx4)(0.f);
#pragma unroll
  for (int kb = 0; kb < 4; ++kb) {
    short8 a = *(const short8*)(aptr + kb * 32);
    int kslot = kb * 4 + (lane >> 4);
#pragma unroll
    for (int n = 0; n < 8; ++n) {
      int col = n * 16 + (lane & 15);
      const ushort* bp = sW + col * 128 + ((kslot ^ (col & 15)) << 3);
      short8 b = *(const short8*)bp;
      acc[n] = __builtin_amdgcn_mfma_f32_16x16x32_bf16(a, b, acc[n], 0, 0, 0);
    }
  }
  int srow_base = row0 + (lane >> 4) * 4;
#pragma unroll
  for (int r = 0; r < 4; ++r) {
    int grow = srow_base + r;
    if (grow < NN) {
      ushort* out = Hb + (size_t)grow * 128 + (lane & 15);
#pragma unroll
      for (int n = 0; n < 8; ++n) out[n * 16] = f2bf(acc[n][r]);
    }
  }
}

// ---------------- pull-mode aggregation, predicated 8-wide batches ----------------
// 16-lane group per node (16B = 8 bf16 channels per lane), 16 nodes/block.
__global__ __launch_bounds__(256) void k_agg(const ushort* __restrict__ H,
                                             const float* __restrict__ bias,
                                             const float* __restrict__ dinv,
                                             const int* __restrict__ offsets,
                                             const int* __restrict__ srcs,
                                             ushort* __restrict__ Hout, int do_relu) {
  int node = blockIdx.x * 16 + (threadIdx.x >> 4);
  if (node >= NN) return;
  int c8 = threadIdx.x & 15;  // 16B slot; channels c8*8 .. c8*8+7
  float di = dinv[node];
  int s = offsets[node], e = offsets[node + 1];
  float acc[8];
#pragma unroll
  for (int j = 0; j < 8; ++j) acc[j] = 0.f;
  for (int i = s; i < e; i += 8) {
    int sx[8];
    float dx[8];
    uint4 vx[8];
#pragma unroll
    for (int u = 0; u < 8; ++u) {
      int idx = i + u;
      bool vld = idx < e;
      sx[u] = srcs[vld ? idx : s];
      dx[u] = vld ? 1.0f : 0.0f;
    }
#pragma unroll
    for (int u = 0; u < 8; ++u) dx[u] *= dinv[sx[u]];
#pragma unroll
    for (int u = 0; u < 8; ++u) vx[u] = *((const uint4*)(H + (size_t)sx[u] * 128) + c8);
#pragma unroll
    for (int u = 0; u < 8; ++u) {
      acc[0] += bflo(vx[u].x) * dx[u];
      acc[1] += bfhi(vx[u].x) * dx[u];
      acc[2] += bflo(vx[u].y) * dx[u];
      acc[3] += bfhi(vx[u].y) * dx[u];
      acc[4] += bflo(vx[u].z) * dx[u];
      acc[5] += bfhi(vx[u].z) * dx[u];
      acc[6] += bflo(vx[u].w) * dx[u];
      acc[7] += bfhi(vx[u].w) * dx[u];
    }
  }
  uint4 hv = *((const uint4*)(H + (size_t)node * 128) + c8);
  float hb[8] = {bflo(hv.x), bfhi(hv.x), bflo(hv.y), bfhi(hv.y),
                 bflo(hv.z), bfhi(hv.z), bflo(hv.w), bfhi(hv.w)};
  float dii = di * di;
  const float* bp = bias + c8 * 8;
  float r[8];
#pragma unroll
  for (int j = 0; j < 8; ++j) {
    float vv = acc[j] * di + hb[j] * dii + bp[j];
    if (do_relu) vv = fmaxf(vv, 0.f);
    r[j] = vv;
  }
  uint4 o;
  o.x = pack2(r[0], r[1]);
  o.y = pack2(r[2], r[3]);
  o.z = pack2(r[4], r[5]);
  o.w = pack2(r[6], r[7]);
  *((uint4*)(Hout + (size_t)node * 128) + c8) = o;
}

// ---------------- global mean pool (batch is sorted), bf16 in ----------------
__device__ inline int lower_bound(const int* a, int n, int v) {
  int lo = 0, hi = n;
  while (lo < hi) {
    int m = (lo + hi) >> 1;
    if (a[m] < v) lo = m + 1; else hi = m;
  }
  return lo;
}

__global__ __launch_bounds__(128) void k_pool(const ushort* __restrict__ H,
                                              const int* __restrict__ batch,
                                              float* __restrict__ f) {
  int g = blockIdx.x;
  int c = threadIdx.x;
  int s = lower_bound(batch, NN, g);
  int e = lower_bound(batch, NN, g + 1);
  float acc = 0.f;
#pragma unroll 4
  for (int i = s; i < e; ++i)
    acc += __uint_as_float(((uint)H[(size_t)i * 128 + c]) << 16);
  f[g * 128 + c] = acc / fmaxf((float)(e - s), 1.0f);
}

// ---------------- MLP as f32 tiled GEMM: Y[M,N] = X[M,K] @ W[K,N] + b ----------------
// 256 threads, 32x64 tile (M x N), BK=32, 2x4 register tile per thread.
__global__ __launch_bounds__(256) void k_mgemm(const float* __restrict__ X,
                                               const float* __restrict__ W,
                                               const float* __restrict__ bias,
                                               float* __restrict__ Y,
                                               int M, int K, int N, int do_relu) {
  __shared__ float sA[32][32];  // [k][m]
  __shared__ float sB[32][64];  // [k][n]
  int t = threadIdx.x;
  int tn = t & 15, tm = t >> 4;
  int m0 = blockIdx.y * 32;
  int n0 = blockIdx.x * 64;
  float acc[2][4];
#pragma unroll
  for (int i = 0; i < 2; ++i)
#pragma unroll
    for (int j = 0; j < 4; ++j) acc[i][j] = 0.f;

  for (int kb = 0; kb < K; kb += 32) {
    {
      int r = t >> 3, kq = t & 7;  // 32 rows x 8 float4
      float4 v = *(const float4*)(X + (size_t)(m0 + r) * K + kb + kq * 4);
      sA[kq * 4 + 0][r] = v.x;
      sA[kq * 4 + 1][r] = v.y;
      sA[kq * 4 + 2][r] = v.z;
      sA[kq * 4 + 3][r] = v.w;
    }
#pragma unroll
    for (int l = 0; l < 2; ++l) {
      int idx = t * 2 + l;
      int kr = idx >> 4, nq = idx & 15;
      *(float4*)&sB[kr][nq * 4] = *(const float4*)(W + (size_t)(kb + kr) * N + n0 + nq * 4);
    }
    __syncthreads();
#pragma unroll
    for (int k = 0; k < 32; ++k) {
      float a[2], b[4];
      a[0] = sA[k][tm * 2];
      a[1] = sA[k][tm * 2 + 1];
      *(float4*)b = *(float4*)&sB[k][tn * 4];
#pragma unroll
      for (int i = 0; i < 2; ++i)
#pragma unroll
        for (int j = 0; j < 4; ++j) acc[i][j] += a[i] * b[j];
    }
    __syncthreads();
  }
  float4 bv = *(const float4*)(bias + n0 + tn * 4);
#pragma unroll
  for (int i = 0; i < 2; ++i) {
    float4 o;
    o.x = acc[i][0] + bv.x;
    o.y = acc[i][1] + bv.y;
    o.z = acc[i][2] + bv.z;
    o.w = acc[i][3] + bv.w;
    if (do_relu) {
      o.x = fmaxf(o.x, 0.f);
      o.y = fmaxf(o.y, 0.f);
      o.z = fmaxf(o.z, 0.f);
      o.w = fmaxf(o.w, 0.f);
    }
    *(float4*)(Y + (size_t)(m0 + tm * 2 + i) * N + n0 + tn * 4) = o;
  }
}

extern "C" void kernel_launch(void* const* d_in, const int* in_sizes, int n_in,
                              void* d_out, int out_size, void* d_ws, size_t ws_size,
                              hipStream_t stream) {
  const float* x    = (const float*)d_in[0];
  const int* ei     = (const int*)d_in[1];
  const int* batch  = (const int*)d_in[2];
  const float* W1   = (const float*)d_in[3];  const float* b1  = (const float*)d_in[4];
  const float* W2   = (const float*)d_in[5];  const float* b2  = (const float*)d_in[6];
  const float* W3   = (const float*)d_in[7];  const float* b3  = (const float*)d_in[8];
  const float* Wf1  = (const float*)d_in[9];  const float* bf1 = (const float*)d_in[10];
  const float* Wf2  = (const float*)d_in[11]; const float* bf2 = (const float*)d_in[12];
  const float* Wf3  = (const float*)d_in[13]; const float* bf3 = (const float*)d_in[14];
  const float* Wf4  = (const float*)d_in[15]; const float* bf4 = (const float*)d_in[16];
  const int* src = ei;
  const int* dst = ei + NE;

  char* ws = (char*)d_ws;
  size_t off = 0;
  auto alloc = [&](size_t bytes) {
    void* p = ws + off;
    off += (bytes + 255) & ~(size_t)255;
    return p;
  };
  ushort* B0     = (ushort*)alloc((size_t)NN * 128 * 2);
  ushort* B1     = (ushort*)alloc((size_t)NN * 128 * 2);
  ushort* B2     = (ushort*)alloc((size_t)NN * 128 * 2);
  float* dinv    = (float*)alloc((size_t)NN * 4);
  int*   offsets = (int*)alloc((size_t)(NN + 1) * 4);
  int*   srcs    = (int*)alloc((size_t)NE * 4);
  uint*  pedge   = (uint*)alloc((size_t)NE * 4);
  int*   phist   = (int*)alloc((size_t)PPART * 4);
  int*   pbase   = (int*)alloc((size_t)(PPART + 1) * 4);
  int*   pcur    = (int*)alloc((size_t)PPART * 4);
  ushort* wt1    = (ushort*)alloc(128 * 128 * 2);
  ushort* wt2    = (ushort*)alloc(128 * 128 * 2);
  ushort* wt3    = (ushort*)alloc(128 * 128 * 2);
  float* t1      = (float*)alloc((size_t)NG * 512 * 4);
  float* t2      = (float*)alloc((size_t)NG * 256 * 4);
  float* t3      = (float*)alloc((size_t)NG * 128 * 4);

  float* f_out = (float*)d_out;             // [512*128]
  float* z_out = (float*)d_out + NG * HID;  // [512*64]

  // ---- preprocessing: partition-count -> scan -> scatter -> in-partition bucket ----
  hipMemsetAsync(phist, 0, (size_t)PPART * 4, stream);
  k_hist<<<(NE + EPB - 1) / EPB, 256, 0, stream>>>(dst, phist);
  k_pscan<<<1, 512, 0, stream>>>(phist, pbase);
  k_pinit<<<(PPART + 255) / 256, 256, 0, stream>>>(pbase, pcur);
  k_part<<<(NE + EPB - 1) / EPB, 256, 0, stream>>>(src, dst, pcur, pedge);
  k_bucket2<<<PPART, 256, 0, stream>>>(pbase, pedge, srcs, offsets, dinv);

  k_prepW<<<128, 128, 0, stream>>>(W1, wt1);
  k_prepW<<<128, 128, 0, stream>>>(W2, wt2);
  k_prepW<<<128, 128, 0, stream>>>(W3, wt3);
  k_cast<<<(NN * 128 / 4 + 255) / 256, 256, 0, stream>>>((const float4*)x, (uint2*)B0, NN * 128 / 4);

  int gemm_grid = (NN + 63) / 64;
  int agg_grid = (NN + 15) / 16;

  // layer 1
  k_gemm<<<gemm_grid, 256, 0, stream>>>(B0, wt1, B1);
  k_agg<<<agg_grid, 256, 0, stream>>>(B1, b1, dinv, offsets, srcs, B2, 1);
  // layer 2
  k_gemm<<<gemm_grid, 256, 0, stream>>>(B2, wt2, B1);
  k_agg<<<agg_grid, 256, 0, stream>>>(B1, b2, dinv, offsets, srcs, B0, 1);
  // layer 3
  k_gemm<<<gemm_grid, 256, 0, stream>>>(B0, wt3, B1);
  k_agg<<<agg_grid, 256, 0, stream>>>(B1, b3, dinv, offsets, srcs, B2, 0);

  k_pool<<<NG, 128, 0, stream>>>(B2, batch, f_out);

  // MLP head as 4 tiled f32 GEMMs over the whole batch (M=512)
  k_mgemm<<<dim3(8, 16), 256, 0, stream>>>(f_out, Wf1, bf1, t1, NG, 128, 512, 1);
  k_mgemm<<<dim3(4, 16), 256, 0, stream>>>(t1, Wf2, bf2, t2, NG, 512, 256, 1);
  k_mgemm<<<dim3(2, 16), 256, 0, stream>>>(t2, Wf3, bf3, t3, NG, 256, 128, 1);
  k_mgemm<<<dim3(1, 16), 256, 0, stream>>>(t3, Wf4, bf4, z_out, NG, 128, 64, 0);
}